// Round 2
// baseline (786.326 us; speedup 1.0000x reference)
//
#include <hip/hip_runtime.h>
#include <stdint.h>

typedef unsigned short u16;
typedef unsigned int u32;
typedef __attribute__((ext_vector_type(8))) __bf16 bf16x8;
typedef __attribute__((ext_vector_type(4))) float f32x4;

#define DEV static __device__ __forceinline__

// ---------- small helpers ----------
DEV u16 f2bf(float f){
  u32 u = __float_as_uint(f);
  u += 0x7fffu + ((u >> 16) & 1u);   // round-to-nearest-even
  return (u16)(u >> 16);
}
DEV float bf2f(u16 h){ return __uint_as_float(((u32)h) << 16); }
DEV float exp2fast(float x){ return __builtin_amdgcn_exp2f(x); }
DEV float log2fast(float x){ return __builtin_amdgcn_logf(x); }
DEV float siluf(float x){ return x / (1.f + exp2fast(-1.44269504f * x)); }
DEV float softplusf(float x){
  if(x > 20.f) return x;
  return 0.69314718056f * log2fast(1.f + exp2fast(1.44269504f * x));
}

#define GLL(gp, lp) __builtin_amdgcn_global_load_lds( \
    (__attribute__((address_space(1))) void*)(gp),    \
    (__attribute__((address_space(3))) void*)(lp), 16, 0, 0)

// ---------- f32 -> bf16 conversion ----------
__global__ __launch_bounds__(256) void f2bf_kernel(const float* __restrict__ in,
                                                   u16* __restrict__ out, int n){
  int i = blockIdx.x * 256 + threadIdx.x;
  if(i < n) out[i] = f2bf(in[i]);
}

// extract dt (first 64 cols of xdbl) as bf16
__global__ __launch_bounds__(256) void dtbf_kernel(const float* __restrict__ xdbl,
                                                   u16* __restrict__ dtb){
  int i = blockIdx.x * 256 + threadIdx.x;    // exactly 8192*64 threads
  int mm = i >> 6, r = i & 63;
  dtb[i] = f2bf(xdbl[mm * 96 + r]);
}

// ---------- LayerNorm (row=1024), writes bf16 ----------
__global__ __launch_bounds__(256) void ln_kernel(const float* __restrict__ x,
    const float* __restrict__ w, const float* __restrict__ bias,
    u16* __restrict__ xn){
  const int m = blockIdx.x;
  const int t = threadIdx.x;
  float4 v = ((const float4*)(x + (size_t)m * 1024))[t];
  float s  = v.x + v.y + v.z + v.w;
  float s2 = v.x*v.x + v.y*v.y + v.z*v.z + v.w*v.w;
#pragma unroll
  for(int o = 32; o; o >>= 1){ s += __shfl_xor(s, o); s2 += __shfl_xor(s2, o); }
  __shared__ float red[8];
  const int wv = t >> 6;
  if((t & 63) == 0){ red[wv] = s; red[4 + wv] = s2; }
  __syncthreads();
  s  = red[0] + red[1] + red[2] + red[3];
  s2 = red[4] + red[5] + red[6] + red[7];
  const float mu  = s * (1.f / 1024.f);
  const float var = s2 * (1.f / 1024.f) - mu * mu;
  const float rs  = rsqrtf(var + 1e-5f);
  float4 wv4 = ((const float4*)w)[t];
  float4 bv4 = ((const float4*)bias)[t];
  u32 o0 = (u32)f2bf((v.x - mu) * rs * wv4.x + bv4.x)
         | ((u32)f2bf((v.y - mu) * rs * wv4.y + bv4.y) << 16);
  u32 o1 = (u32)f2bf((v.z - mu) * rs * wv4.z + bv4.z)
         | ((u32)f2bf((v.w - mu) * rs * wv4.w + bv4.w) << 16);
  uint2 o = {o0, o1};
  ((uint2*)(xn + (size_t)m * 1024))[t] = o;
}

// ---------- bf16 MFMA GEMM:  C[M][N] = A[M][K] * W[N][K]^T  (NT) ----------
// 128 x BN tile, BK=32, 4 waves as 2x2, each wave 64 x (BN/2).
// EPI: 0 = f32 store
//      1 = bf16 store of softplus(acc + ep[n])          (dt_proj -> delta)
//      2 = f32 store of acc + ep[m*ldc+n]               (out_proj + residual)
//      3 = bf16 split store: col<2048 -> C0, else C1    (in_proj u/z halves)
template<int BN, int FN, int EPI>
__global__ __launch_bounds__(256) void gemm_nt(
    const u16* __restrict__ A, const u16* __restrict__ W,
    void* __restrict__ Cv, void* __restrict__ C2v,
    const float* __restrict__ ep, int K, int ldc)
{
  constexpr int WN   = BN / 2;
  constexpr int NCHB = (BN * 64) / 1024;   // 1KB chunks in B tile
  __shared__ alignas(16) u16 As[128 * 32];
  __shared__ alignas(16) u16 Bs[BN * 32];

  const int tid  = threadIdx.x;
  const int wave = tid >> 6, lane = tid & 63;
  const int wm = wave >> 1, wn = wave & 1;
  const int lr = lane & 15, lg = lane >> 4;
  const int m0 = blockIdx.x * 128, n0 = blockIdx.y * BN;

  f32x4 acc[4][FN];
  const f32x4 z4 = {0.f, 0.f, 0.f, 0.f};
#pragma unroll
  for(int i = 0; i < 4; i++)
#pragma unroll
    for(int j = 0; j < FN; j++) acc[i][j] = z4;

  for(int k0 = 0; k0 < K; k0 += 32){
    // stage A tile (128x32 bf16 = 8KB): 8 x 1KB chunks, 2 per wave
#pragma unroll
    for(int i = 0; i < 2; i++){
      int off = (wave + 4 * i) * 1024 + lane * 16;   // byte offset in tile
      int row = off >> 6, cbyte = off & 63;
      GLL(A + (size_t)(m0 + row) * K + k0 + (cbyte >> 1), (char*)As + off);
    }
    // stage B tile (BN x 32 bf16)
    for(int ch = wave; ch < NCHB; ch += 4){
      int off = ch * 1024 + lane * 16;
      int row = off >> 6, cbyte = off & 63;
      GLL(W + (size_t)(n0 + row) * K + k0 + (cbyte >> 1), (char*)Bs + off);
    }
    __syncthreads();

    bf16x8 af[4], bfr[FN];
#pragma unroll
    for(int fm = 0; fm < 4; fm++)
      af[fm] = *(const bf16x8*)(As + (wm * 64 + fm * 16 + lr) * 32 + lg * 8);
#pragma unroll
    for(int fn = 0; fn < FN; fn++)
      bfr[fn] = *(const bf16x8*)(Bs + (wn * WN + fn * 16 + lr) * 32 + lg * 8);
#pragma unroll
    for(int fm = 0; fm < 4; fm++)
#pragma unroll
      for(int fn = 0; fn < FN; fn++)
        acc[fm][fn] = __builtin_amdgcn_mfma_f32_16x16x32_bf16(af[fm], bfr[fn], acc[fm][fn], 0, 0, 0);
    __syncthreads();
  }

  // epilogue: C/D layout col = lane&15, row = (lane>>4)*4 + j  [verified]
#pragma unroll
  for(int fm = 0; fm < 4; fm++){
#pragma unroll
    for(int fn = 0; fn < FN; fn++){
      int cc = n0 + wn * WN + fn * 16 + lr;
      int r0 = m0 + wm * 64 + fm * 16 + lg * 4;
      f32x4 a = acc[fm][fn];
#pragma unroll
      for(int j = 0; j < 4; j++){
        float v = a[j];
        int r = r0 + j;
        size_t idx = (size_t)r * ldc + cc;
        if constexpr(EPI == 0){
          ((float*)Cv)[idx] = v;
        } else if constexpr(EPI == 1){
          ((u16*)Cv)[idx] = f2bf(softplusf(v + ep[cc]));
        } else if constexpr(EPI == 2){
          ((float*)Cv)[idx] = v + ep[idx];
        } else {
          if(cc < 2048) ((u16*)Cv)[(size_t)r * 2048 + cc] = f2bf(v);
          else          ((u16*)C2v)[(size_t)r * 2048 + cc - 2048] = f2bf(v);
        }
      }
    }
  }
}

// ---------- depthwise causal conv (k=4) + bias + SiLU, bf16 in/out ----------
__global__ __launch_bounds__(256) void conv_kernel(
    const u16* __restrict__ ub, const float* __restrict__ cw,
    const float* __restrict__ cb, u16* __restrict__ uc)
{
  const int m = blockIdx.x;          // b*L + l
  const int l = m & 2047;
  const int d0 = threadIdx.x * 8;
  float4 w4[8];
#pragma unroll
  for(int i = 0; i < 8; i++) w4[i] = *(const float4*)(cw + (size_t)(d0 + i) * 4);
  float r[4][8];
#pragma unroll
  for(int j = 0; j < 4; j++)
#pragma unroll
    for(int i = 0; i < 8; i++) r[j][i] = 0.f;
  for(int j = 0; j < 4; j++){
    if(l - 3 + j < 0) continue;
    uint4 a = *(const uint4*)(ub + (size_t)(m - 3 + j) * 2048 + d0);
    u32 w0 = a.x, w1 = a.y, w2 = a.z, w3 = a.w;
    r[j][0] = bf2f((u16)(w0 & 0xffff)); r[j][1] = bf2f((u16)(w0 >> 16));
    r[j][2] = bf2f((u16)(w1 & 0xffff)); r[j][3] = bf2f((u16)(w1 >> 16));
    r[j][4] = bf2f((u16)(w2 & 0xffff)); r[j][5] = bf2f((u16)(w2 >> 16));
    r[j][6] = bf2f((u16)(w3 & 0xffff)); r[j][7] = bf2f((u16)(w3 >> 16));
  }
  float4 b0 = *(const float4*)(cb + d0), b1 = *(const float4*)(cb + d0 + 4);
  float bb[8] = {b0.x, b0.y, b0.z, b0.w, b1.x, b1.y, b1.z, b1.w};
  u32 outw[4];
#pragma unroll
  for(int i = 0; i < 4; i++){
    int e0 = 2 * i, e1 = 2 * i + 1;
    float v0 = bb[e0] + r[0][e0]*w4[e0].x + r[1][e0]*w4[e0].y + r[2][e0]*w4[e0].z + r[3][e0]*w4[e0].w;
    float v1 = bb[e1] + r[0][e1]*w4[e1].x + r[1][e1]*w4[e1].y + r[2][e1]*w4[e1].z + r[3][e1]*w4[e1].w;
    outw[i] = (u32)f2bf(siluf(v0)) | ((u32)f2bf(siluf(v1)) << 16);
  }
  uint4 o = {outw[0], outw[1], outw[2], outw[3]};
  *(uint4*)(uc + (size_t)m * 2048 + d0) = o;
}

// ---------- selective scan ----------
// 512 blocks x 256 threads. Block owns 16 channels (b fixed, d0..d0+15);
// 16 lanes per channel = one state each. LDS-staged windows of 32 timesteps.
__global__ __launch_bounds__(256) void scan_kernel(
    const u16* __restrict__ deltab, const u16* __restrict__ uc,
    const float* __restrict__ xdbl, const u16* __restrict__ zb,
    const float* __restrict__ A_log, const float* __restrict__ Dv,
    u16* __restrict__ ybf)
{
  __shared__ u16   sd[32][16];
  __shared__ u16   su[32][16];
  __shared__ float sBC[32][32];
  __shared__ u16   sz[32][16];
  __shared__ u16   sy[32][16];

  const int t  = threadIdx.x;
  const int c0 = blockIdx.x * 16;
  const int b  = c0 >> 11;
  const int d0 = c0 & 2047;
  const int ch = t >> 4, s = t & 15;
  const int d  = d0 + ch;

  const float a2 = -expf(A_log[d * 16 + s]) * 1.44269504f;  // A * log2(e)
  const float Dd = Dv[d];
  const int lrow = t >> 3, li = t & 7;
  float h = 0.f;

  for(int w = 0; w < 64; ++w){
    {
      size_t m = (size_t)b * 2048 + w * 32 + lrow;
      *(u32*)&sd[lrow][li * 2]     = *(const u32*)(deltab + m * 2048 + d0 + li * 2);
      *(u32*)&su[lrow][li * 2]     = *(const u32*)(uc + m * 2048 + d0 + li * 2);
      *(float4*)&sBC[lrow][li * 4] = *(const float4*)(xdbl + m * 96 + 64 + li * 4);
      *(u32*)&sz[lrow][li * 2]     = *(const u32*)(zb + m * 2048 + d0 + li * 2);
    }
    __syncthreads();
#pragma unroll 4
    for(int l = 0; l < 32; l++){
      float dt = bf2f(sd[l][ch]);
      float u  = bf2f(su[l][ch]);
      float Bt = sBC[l][s];
      float Ct = sBC[l][16 + s];
      float e  = exp2fast(dt * a2);
      h = e * h + (dt * u) * Bt;
      float p = h * Ct;
      p += __shfl_xor(p, 1); p += __shfl_xor(p, 2);
      p += __shfl_xor(p, 4); p += __shfl_xor(p, 8);
      if(s == 0){
        float z = bf2f(sz[l][ch]);
        float y = (p + Dd * u) * siluf(z);
        sy[l][ch] = f2bf(y);
      }
    }
    __syncthreads();
    {
      size_t m = (size_t)b * 2048 + w * 32 + lrow;
      *(u32*)(ybf + m * 2048 + d0 + li * 2) = *(const u32*)&sy[lrow][li * 2];
    }
  }
}

// ---------- launch ----------
extern "C" void kernel_launch(void* const* d_in, const int* in_sizes, int n_in,
                              void* d_out, int out_size, void* d_ws, size_t ws_size,
                              hipStream_t stream) {
  (void)in_sizes; (void)n_in; (void)out_size; (void)ws_size;
  const float* x         = (const float*)d_in[0];
  const float* norm_w    = (const float*)d_in[1];
  const float* norm_b    = (const float*)d_in[2];
  const float* in_proj_w = (const float*)d_in[3];
  const float* conv_w    = (const float*)d_in[4];
  const float* conv_b    = (const float*)d_in[5];
  const float* x_proj_w  = (const float*)d_in[6];
  const float* dt_proj_w = (const float*)d_in[7];
  const float* dt_proj_b = (const float*)d_in[8];
  const float* A_log     = (const float*)d_in[9];
  const float* Dv        = (const float*)d_in[10];
  const float* out_proj_w= (const float*)d_in[11];
  float* out = (float*)d_out;

  // workspace layout (~168 MB total)
  char* ws = (char*)d_ws;
  u16*   w_in  = (u16*)ws;  ws += (size_t)4096 * 1024 * 2;   //  8.4 MB
  u16*   w_xp  = (u16*)ws;  ws += (size_t)96 * 2048 * 2;     //  0.4 MB
  u16*   w_dt  = (u16*)ws;  ws += (size_t)2048 * 64 * 2;     //  0.3 MB
  u16*   w_op  = (u16*)ws;  ws += (size_t)1024 * 2048 * 2;   //  4.2 MB
  u16*   xn    = (u16*)ws;  ws += (size_t)8192 * 1024 * 2;   // 16.8 MB
  u16*   u_bf  = (u16*)ws;  ws += (size_t)8192 * 2048 * 2;   // 33.5 MB (ybf aliases after conv)
  u16*   z_bf  = (u16*)ws;  ws += (size_t)8192 * 2048 * 2;   // 33.5 MB
  u16*   ucbf  = (u16*)ws;  ws += (size_t)8192 * 2048 * 2;   // 33.5 MB
  float* xdbl  = (float*)ws; ws += (size_t)8192 * 96 * 4;    //  3.1 MB
  u16*   dtbf  = (u16*)ws;  ws += (size_t)8192 * 64 * 2;     //  1.0 MB
  u16*   deltab= (u16*)ws;  ws += (size_t)8192 * 2048 * 2;   // 33.5 MB
  u16*   ybf   = u_bf;   // u dead after conv; reuse for y

  // weight conversions
  f2bf_kernel<<<16384, 256, 0, stream>>>(in_proj_w,  w_in, 4096 * 1024);
  f2bf_kernel<<<768,   256, 0, stream>>>(x_proj_w,   w_xp, 96 * 2048);
  f2bf_kernel<<<512,   256, 0, stream>>>(dt_proj_w,  w_dt, 2048 * 64);
  f2bf_kernel<<<8192,  256, 0, stream>>>(out_proj_w, w_op, 1024 * 2048);

  // 1. layernorm -> bf16
  ln_kernel<<<8192, 256, 0, stream>>>(x, norm_w, norm_b, xn);
  // 2. in_proj: u/z bf16 halves = xn @ in_proj_w^T
  gemm_nt<128, 4, 3><<<dim3(64, 32), 256, 0, stream>>>(xn, w_in, u_bf, z_bf, nullptr, 1024, 4096);
  // 3. depthwise conv + SiLU -> bf16
  conv_kernel<<<8192, 256, 0, stream>>>(u_bf, conv_w, conv_b, ucbf);
  // 4. x_proj: xdbl[8192][96] = uc @ x_proj_w^T
  gemm_nt<96, 3, 0><<<dim3(64, 1), 256, 0, stream>>>(ucbf, w_xp, xdbl, nullptr, nullptr, 2048, 96);
  // 5. dt -> bf16
  dtbf_kernel<<<2048, 256, 0, stream>>>(xdbl, dtbf);
  // 6. dt_proj + bias + softplus -> bf16 delta[8192][2048]
  gemm_nt<128, 4, 1><<<dim3(64, 16), 256, 0, stream>>>(dtbf, w_dt, deltab, nullptr, dt_proj_b, 64, 2048);
  // 7. selective scan + gate -> bf16 y (into u_bf region)
  scan_kernel<<<512, 256, 0, stream>>>(deltab, ucbf, xdbl, z_bf, A_log, Dv, ybf);
  // 8. out_proj + residual: out[8192][1024] f32
  gemm_nt<128, 4, 2><<<dim3(64, 8), 256, 0, stream>>>(ybf, w_op, out, nullptr, x, 2048, 1024);
}

// Round 3
// 401.308 us; speedup vs baseline: 1.9594x; 1.9594x over previous
//
#include <hip/hip_runtime.h>
#include <stdint.h>

typedef unsigned short u16;
typedef unsigned int u32;
typedef __attribute__((ext_vector_type(8))) __bf16 bf16x8;
typedef __attribute__((ext_vector_type(4))) float f32x4;

#define DEV static __device__ __forceinline__

// ---------- small helpers ----------
DEV u16 f2bf(float f){
  u32 u = __float_as_uint(f);
  u += 0x7fffu + ((u >> 16) & 1u);   // round-to-nearest-even
  return (u16)(u >> 16);
}
DEV float bf2f(u16 h){ return __uint_as_float(((u32)h) << 16); }
DEV float exp2fast(float x){ return __builtin_amdgcn_exp2f(x); }
DEV float log2fast(float x){ return __builtin_amdgcn_logf(x); }
DEV float siluf(float x){ return x / (1.f + exp2fast(-1.44269504f * x)); }
DEV float softplusf(float x){
  if(x > 20.f) return x;
  return 0.69314718056f * log2fast(1.f + exp2fast(1.44269504f * x));
}

#define GLL(gp, lp) __builtin_amdgcn_global_load_lds( \
    (__attribute__((address_space(1))) void*)(gp),    \
    (__attribute__((address_space(3))) void*)(lp), 16, 0, 0)

// ---------- f32 -> bf16 conversion ----------
__global__ __launch_bounds__(256) void f2bf_kernel(const float* __restrict__ in,
                                                   u16* __restrict__ out, int n){
  int i = blockIdx.x * 256 + threadIdx.x;
  if(i < n) out[i] = f2bf(in[i]);
}

// extract dt (first 64 cols of xdbl) as bf16
__global__ __launch_bounds__(256) void dtbf_kernel(const float* __restrict__ xdbl,
                                                   u16* __restrict__ dtb){
  int i = blockIdx.x * 256 + threadIdx.x;    // exactly 8192*64 threads
  int mm = i >> 6, r = i & 63;
  dtb[i] = f2bf(xdbl[mm * 96 + r]);
}

// ---------- LayerNorm (row=1024), writes bf16 ----------
__global__ __launch_bounds__(256) void ln_kernel(const float* __restrict__ x,
    const float* __restrict__ w, const float* __restrict__ bias,
    u16* __restrict__ xn){
  const int m = blockIdx.x;
  const int t = threadIdx.x;
  float4 v = ((const float4*)(x + (size_t)m * 1024))[t];
  float s  = v.x + v.y + v.z + v.w;
  float s2 = v.x*v.x + v.y*v.y + v.z*v.z + v.w*v.w;
#pragma unroll
  for(int o = 32; o; o >>= 1){ s += __shfl_xor(s, o); s2 += __shfl_xor(s2, o); }
  __shared__ float red[8];
  const int wv = t >> 6;
  if((t & 63) == 0){ red[wv] = s; red[4 + wv] = s2; }
  __syncthreads();
  s  = red[0] + red[1] + red[2] + red[3];
  s2 = red[4] + red[5] + red[6] + red[7];
  const float mu  = s * (1.f / 1024.f);
  const float var = s2 * (1.f / 1024.f) - mu * mu;
  const float rs  = rsqrtf(var + 1e-5f);
  float4 wv4 = ((const float4*)w)[t];
  float4 bv4 = ((const float4*)bias)[t];
  u32 o0 = (u32)f2bf((v.x - mu) * rs * wv4.x + bv4.x)
         | ((u32)f2bf((v.y - mu) * rs * wv4.y + bv4.y) << 16);
  u32 o1 = (u32)f2bf((v.z - mu) * rs * wv4.z + bv4.z)
         | ((u32)f2bf((v.w - mu) * rs * wv4.w + bv4.w) << 16);
  uint2 o = {o0, o1};
  ((uint2*)(xn + (size_t)m * 1024))[t] = o;
}

// ---------- bf16 MFMA GEMM:  C[M][N] = A[M][K] * W[N][K]^T  (NT) ----------
// 128 x BN tile, BK=32, 4 waves as 2x2, each wave 64 x (BN/2).
// EPI: 0 = f32 store
//      1 = bf16 store of softplus(acc + ep[n])          (dt_proj -> delta)
//      2 = f32 store of acc + ep[m*ldc+n]               (out_proj + residual)
//      3 = bf16 split store: col<2048 -> C0, else C1    (in_proj u/z halves)
template<int BN, int FN, int EPI>
__global__ __launch_bounds__(256) void gemm_nt(
    const u16* __restrict__ A, const u16* __restrict__ W,
    void* __restrict__ Cv, void* __restrict__ C2v,
    const float* __restrict__ ep, int K, int ldc)
{
  constexpr int WN   = BN / 2;
  constexpr int NCHB = (BN * 64) / 1024;   // 1KB chunks in B tile
  __shared__ alignas(16) u16 As[128 * 32];
  __shared__ alignas(16) u16 Bs[BN * 32];

  const int tid  = threadIdx.x;
  const int wave = tid >> 6, lane = tid & 63;
  const int wm = wave >> 1, wn = wave & 1;
  const int lr = lane & 15, lg = lane >> 4;
  const int m0 = blockIdx.x * 128, n0 = blockIdx.y * BN;

  f32x4 acc[4][FN];
  const f32x4 z4 = {0.f, 0.f, 0.f, 0.f};
#pragma unroll
  for(int i = 0; i < 4; i++)
#pragma unroll
    for(int j = 0; j < FN; j++) acc[i][j] = z4;

  for(int k0 = 0; k0 < K; k0 += 32){
    // stage A tile (128x32 bf16 = 8KB): 8 x 1KB chunks, 2 per wave
#pragma unroll
    for(int i = 0; i < 2; i++){
      int off = (wave + 4 * i) * 1024 + lane * 16;   // byte offset in tile
      int row = off >> 6, cbyte = off & 63;
      GLL(A + (size_t)(m0 + row) * K + k0 + (cbyte >> 1), (char*)As + off);
    }
    // stage B tile (BN x 32 bf16)
    for(int ch = wave; ch < NCHB; ch += 4){
      int off = ch * 1024 + lane * 16;
      int row = off >> 6, cbyte = off & 63;
      GLL(W + (size_t)(n0 + row) * K + k0 + (cbyte >> 1), (char*)Bs + off);
    }
    __syncthreads();

    bf16x8 af[4], bfr[FN];
#pragma unroll
    for(int fm = 0; fm < 4; fm++)
      af[fm] = *(const bf16x8*)(As + (wm * 64 + fm * 16 + lr) * 32 + lg * 8);
#pragma unroll
    for(int fn = 0; fn < FN; fn++)
      bfr[fn] = *(const bf16x8*)(Bs + (wn * WN + fn * 16 + lr) * 32 + lg * 8);
#pragma unroll
    for(int fm = 0; fm < 4; fm++)
#pragma unroll
      for(int fn = 0; fn < FN; fn++)
        acc[fm][fn] = __builtin_amdgcn_mfma_f32_16x16x32_bf16(af[fm], bfr[fn], acc[fm][fn], 0, 0, 0);
    __syncthreads();
  }

  // epilogue: C/D layout col = lane&15, row = (lane>>4)*4 + j  [verified]
#pragma unroll
  for(int fm = 0; fm < 4; fm++){
#pragma unroll
    for(int fn = 0; fn < FN; fn++){
      int cc = n0 + wn * WN + fn * 16 + lr;
      int r0 = m0 + wm * 64 + fm * 16 + lg * 4;
      f32x4 a = acc[fm][fn];
#pragma unroll
      for(int j = 0; j < 4; j++){
        float v = a[j];
        int r = r0 + j;
        size_t idx = (size_t)r * ldc + cc;
        if constexpr(EPI == 0){
          ((float*)Cv)[idx] = v;
        } else if constexpr(EPI == 1){
          ((u16*)Cv)[idx] = f2bf(softplusf(v + ep[cc]));
        } else if constexpr(EPI == 2){
          ((float*)Cv)[idx] = v + ep[idx];
        } else {
          if(cc < 2048) ((u16*)Cv)[(size_t)r * 2048 + cc] = f2bf(v);
          else          ((u16*)C2v)[(size_t)r * 2048 + cc - 2048] = f2bf(v);
        }
      }
    }
  }
}

// ---------- depthwise causal conv (k=4) + bias + SiLU, bf16 in/out ----------
__global__ __launch_bounds__(256) void conv_kernel(
    const u16* __restrict__ ub, const float* __restrict__ cw,
    const float* __restrict__ cb, u16* __restrict__ uc)
{
  const int m = blockIdx.x;          // b*L + l
  const int l = m & 2047;
  const int d0 = threadIdx.x * 8;
  float4 w4[8];
#pragma unroll
  for(int i = 0; i < 8; i++) w4[i] = *(const float4*)(cw + (size_t)(d0 + i) * 4);
  float r[4][8];
#pragma unroll
  for(int j = 0; j < 4; j++)
#pragma unroll
    for(int i = 0; i < 8; i++) r[j][i] = 0.f;
  for(int j = 0; j < 4; j++){
    if(l - 3 + j < 0) continue;
    uint4 a = *(const uint4*)(ub + (size_t)(m - 3 + j) * 2048 + d0);
    u32 w0 = a.x, w1 = a.y, w2 = a.z, w3 = a.w;
    r[j][0] = bf2f((u16)(w0 & 0xffff)); r[j][1] = bf2f((u16)(w0 >> 16));
    r[j][2] = bf2f((u16)(w1 & 0xffff)); r[j][3] = bf2f((u16)(w1 >> 16));
    r[j][4] = bf2f((u16)(w2 & 0xffff)); r[j][5] = bf2f((u16)(w2 >> 16));
    r[j][6] = bf2f((u16)(w3 & 0xffff)); r[j][7] = bf2f((u16)(w3 >> 16));
  }
  float4 b0 = *(const float4*)(cb + d0), b1 = *(const float4*)(cb + d0 + 4);
  float bb[8] = {b0.x, b0.y, b0.z, b0.w, b1.x, b1.y, b1.z, b1.w};
  u32 outw[4];
#pragma unroll
  for(int i = 0; i < 4; i++){
    int e0 = 2 * i, e1 = 2 * i + 1;
    float v0 = bb[e0] + r[0][e0]*w4[e0].x + r[1][e0]*w4[e0].y + r[2][e0]*w4[e0].z + r[3][e0]*w4[e0].w;
    float v1 = bb[e1] + r[0][e1]*w4[e1].x + r[1][e1]*w4[e1].y + r[2][e1]*w4[e1].z + r[3][e1]*w4[e1].w;
    outw[i] = (u32)f2bf(siluf(v0)) | ((u32)f2bf(siluf(v1)) << 16);
  }
  uint4 o = {outw[0], outw[1], outw[2], outw[3]};
  *(uint4*)(uc + (size_t)m * 2048 + d0) = o;
}

// ================= selective scan: chunk-parallel, 1 lane = 1 channel ======
// L=2048 split into NC=16 chunks of CL=128. Window W=16 timesteps in LDS.
// grid (8 dgroups, 16 chunks, 4 batches), 256 threads; lane ch = tid, holds
// all 16 states of channel d = dg*256+tid in registers.

// pass A: chunk-local scan (h_in=0) -> H[s] (final h), P[s] (prod of decay)
__global__ __launch_bounds__(256) void scanA_kernel(
    const u16* __restrict__ deltab, const u16* __restrict__ uc,
    const float* __restrict__ xdbl, const float* __restrict__ A_log,
    float* __restrict__ Hc, float* __restrict__ Pc)
{
  __shared__ u16   sd[16][256];
  __shared__ u16   su[16][256];
  __shared__ float sB[16][16];
  const int tid = threadIdx.x;
  const int dg = blockIdx.x, chunk = blockIdx.y, b = blockIdx.z;
  const int d  = dg * 256 + tid;

  float a2[16], h[16], P[16];
#pragma unroll
  for(int q = 0; q < 4; q++){
    float4 al = *(const float4*)(A_log + (size_t)d * 16 + q * 4);
    a2[q*4+0] = -expf(al.x) * 1.44269504f;
    a2[q*4+1] = -expf(al.y) * 1.44269504f;
    a2[q*4+2] = -expf(al.z) * 1.44269504f;
    a2[q*4+3] = -expf(al.w) * 1.44269504f;
  }
#pragma unroll
  for(int s = 0; s < 16; s++){ h[s] = 0.f; P[s] = 1.f; }

  for(int w = 0; w < 8; w++){
    const size_t m0 = (size_t)b * 2048 + chunk * 128 + w * 16;
    // stage dt,u: [16][256] u16 = 512 uint4 each; 2 per thread
#pragma unroll
    for(int i = 0; i < 2; i++){
      int fo = tid + i * 256;
      int row = fo >> 5, col = (fo & 31) * 8;
      *(uint4*)&sd[row][col] = *(const uint4*)(deltab + (m0 + row) * 2048 + dg * 256 + col);
      *(uint4*)&su[row][col] = *(const uint4*)(uc     + (m0 + row) * 2048 + dg * 256 + col);
    }
    // stage B: [16][16] f32 = 64 uint4; threads 0..63
    if(tid < 64){
      int row = tid >> 2, col = (tid & 3) * 4;
      *(float4*)&sB[row][col] = *(const float4*)(xdbl + (m0 + row) * 96 + 64 + col);
    }
    __syncthreads();
#pragma unroll 2
    for(int l = 0; l < 16; l++){
      float dt = bf2f(sd[l][tid]);
      float u  = bf2f(su[l][tid]);
      float du = dt * u;
      float4 B0 = *(const float4*)&sB[l][0];
      float4 B1 = *(const float4*)&sB[l][4];
      float4 B2 = *(const float4*)&sB[l][8];
      float4 B3 = *(const float4*)&sB[l][12];
      float Bv[16] = {B0.x,B0.y,B0.z,B0.w,B1.x,B1.y,B1.z,B1.w,
                      B2.x,B2.y,B2.z,B2.w,B3.x,B3.y,B3.z,B3.w};
#pragma unroll
      for(int s = 0; s < 16; s++){
        float e = exp2fast(dt * a2[s]);
        P[s] *= e;
        h[s] = __builtin_fmaf(e, h[s], du * Bv[s]);
      }
    }
    __syncthreads();
  }
  const size_t base = (((size_t)b * 16 + chunk) * 2048 + d) * 16;
#pragma unroll
  for(int q = 0; q < 4; q++){
    float4 hv = {h[q*4], h[q*4+1], h[q*4+2], h[q*4+3]};
    float4 pv = {P[q*4], P[q*4+1], P[q*4+2], P[q*4+3]};
    *(float4*)(Hc + base + q * 4) = hv;
    *(float4*)(Pc + base + q * 4) = pv;
  }
}

// pass B: serial combine over chunks: h_in[c+1] = H[c] + P[c]*h_in[c]
__global__ __launch_bounds__(256) void scanB_kernel(
    const float* __restrict__ Hc, const float* __restrict__ Pc,
    float* __restrict__ Hin)
{
  const int e = blockIdx.x * 256 + threadIdx.x;    // 131072 = 4*2048*16
  const int b = e >> 15, rem = e & 32767;          // rem = d*16+s
  float hin = 0.f;
  for(int c = 0; c < 16; c++){
    size_t idx = (((size_t)b * 16 + c) << 15) + rem;
    Hin[idx] = hin;
    hin = __builtin_fmaf(Pc[idx], hin, Hc[idx]);
  }
}

// pass C: full per-chunk scan seeded with Hin; y = (sum h*C + D*u)*silu(z)
__global__ __launch_bounds__(256) void scanC_kernel(
    const u16* __restrict__ deltab, const u16* __restrict__ uc,
    const float* __restrict__ xdbl, const u16* __restrict__ zb,
    const float* __restrict__ A_log, const float* __restrict__ Dv,
    const float* __restrict__ Hin, u16* __restrict__ ybf)
{
  __shared__ u16   sd[16][256];
  __shared__ u16   su[16][256];
  __shared__ u16   sz[16][256];
  __shared__ float sBC[16][32];
  __shared__ u16   sy[16][256];
  const int tid = threadIdx.x;
  const int dg = blockIdx.x, chunk = blockIdx.y, b = blockIdx.z;
  const int d  = dg * 256 + tid;

  float a2[16], h[16];
#pragma unroll
  for(int q = 0; q < 4; q++){
    float4 al = *(const float4*)(A_log + (size_t)d * 16 + q * 4);
    a2[q*4+0] = -expf(al.x) * 1.44269504f;
    a2[q*4+1] = -expf(al.y) * 1.44269504f;
    a2[q*4+2] = -expf(al.z) * 1.44269504f;
    a2[q*4+3] = -expf(al.w) * 1.44269504f;
  }
  const size_t hbase = (((size_t)b * 16 + chunk) * 2048 + d) * 16;
#pragma unroll
  for(int q = 0; q < 4; q++){
    float4 hv = *(const float4*)(Hin + hbase + q * 4);
    h[q*4] = hv.x; h[q*4+1] = hv.y; h[q*4+2] = hv.z; h[q*4+3] = hv.w;
  }
  const float Dd = Dv[d];

  for(int w = 0; w < 8; w++){
    const size_t m0 = (size_t)b * 2048 + chunk * 128 + w * 16;
#pragma unroll
    for(int i = 0; i < 2; i++){
      int fo = tid + i * 256;
      int row = fo >> 5, col = (fo & 31) * 8;
      *(uint4*)&sd[row][col] = *(const uint4*)(deltab + (m0 + row) * 2048 + dg * 256 + col);
      *(uint4*)&su[row][col] = *(const uint4*)(uc     + (m0 + row) * 2048 + dg * 256 + col);
      *(uint4*)&sz[row][col] = *(const uint4*)(zb     + (m0 + row) * 2048 + dg * 256 + col);
    }
    if(tid < 128){
      int row = tid >> 3, col = (tid & 7) * 4;
      *(float4*)&sBC[row][col] = *(const float4*)(xdbl + (m0 + row) * 96 + 64 + col);
    }
    __syncthreads();
#pragma unroll 2
    for(int l = 0; l < 16; l++){
      float dt = bf2f(sd[l][tid]);
      float u  = bf2f(su[l][tid]);
      float du = dt * u;
      float4 B0 = *(const float4*)&sBC[l][0];
      float4 B1 = *(const float4*)&sBC[l][4];
      float4 B2 = *(const float4*)&sBC[l][8];
      float4 B3 = *(const float4*)&sBC[l][12];
      float4 C0 = *(const float4*)&sBC[l][16];
      float4 C1 = *(const float4*)&sBC[l][20];
      float4 C2 = *(const float4*)&sBC[l][24];
      float4 C3 = *(const float4*)&sBC[l][28];
      float Bv[16] = {B0.x,B0.y,B0.z,B0.w,B1.x,B1.y,B1.z,B1.w,
                      B2.x,B2.y,B2.z,B2.w,B3.x,B3.y,B3.z,B3.w};
      float Cv[16] = {C0.x,C0.y,C0.z,C0.w,C1.x,C1.y,C1.z,C1.w,
                      C2.x,C2.y,C2.z,C2.w,C3.x,C3.y,C3.z,C3.w};
      float y = 0.f;
#pragma unroll
      for(int s = 0; s < 16; s++){
        float e = exp2fast(dt * a2[s]);
        h[s] = __builtin_fmaf(e, h[s], du * Bv[s]);
        y = __builtin_fmaf(h[s], Cv[s], y);
      }
      float z = bf2f(sz[l][tid]);
      y = (y + Dd * u) * siluf(z);
      sy[l][tid] = f2bf(y);
    }
    __syncthreads();
#pragma unroll
    for(int i = 0; i < 2; i++){
      int fo = tid + i * 256;
      int row = fo >> 5, col = (fo & 31) * 8;
      *(uint4*)(ybf + (m0 + row) * 2048 + dg * 256 + col) = *(const uint4*)&sy[row][col];
    }
  }
}

// ---------- launch ----------
extern "C" void kernel_launch(void* const* d_in, const int* in_sizes, int n_in,
                              void* d_out, int out_size, void* d_ws, size_t ws_size,
                              hipStream_t stream) {
  (void)in_sizes; (void)n_in; (void)out_size; (void)ws_size;
  const float* x         = (const float*)d_in[0];
  const float* norm_w    = (const float*)d_in[1];
  const float* norm_b    = (const float*)d_in[2];
  const float* in_proj_w = (const float*)d_in[3];
  const float* conv_w    = (const float*)d_in[4];
  const float* conv_b    = (const float*)d_in[5];
  const float* x_proj_w  = (const float*)d_in[6];
  const float* dt_proj_w = (const float*)d_in[7];
  const float* dt_proj_b = (const float*)d_in[8];
  const float* A_log     = (const float*)d_in[9];
  const float* Dv        = (const float*)d_in[10];
  const float* out_proj_w= (const float*)d_in[11];
  float* out = (float*)d_out;

  // workspace layout (~185 MB total)
  char* ws = (char*)d_ws;
  u16*   w_in  = (u16*)ws;  ws += (size_t)4096 * 1024 * 2;   //  8.4 MB
  u16*   w_xp  = (u16*)ws;  ws += (size_t)96 * 2048 * 2;     //  0.4 MB
  u16*   w_dt  = (u16*)ws;  ws += (size_t)2048 * 64 * 2;     //  0.3 MB
  u16*   w_op  = (u16*)ws;  ws += (size_t)1024 * 2048 * 2;   //  4.2 MB
  u16*   xn    = (u16*)ws;  ws += (size_t)8192 * 1024 * 2;   // 16.8 MB (dead after in_proj; Hin aliases)
  u16*   u_bf  = (u16*)ws;  ws += (size_t)8192 * 2048 * 2;   // 33.5 MB (ybf aliases after conv)
  u16*   z_bf  = (u16*)ws;  ws += (size_t)8192 * 2048 * 2;   // 33.5 MB
  u16*   ucbf  = (u16*)ws;  ws += (size_t)8192 * 2048 * 2;   // 33.5 MB
  float* xdbl  = (float*)ws; ws += (size_t)8192 * 96 * 4;    //  3.1 MB
  u16*   dtbf  = (u16*)ws;  ws += (size_t)8192 * 64 * 2;     //  1.0 MB
  u16*   deltab= (u16*)ws;  ws += (size_t)8192 * 2048 * 2;   // 33.5 MB
  float* Hc    = (float*)ws; ws += (size_t)4 * 16 * 2048 * 16 * 4;  // 8.4 MB
  float* Pc    = (float*)ws; ws += (size_t)4 * 16 * 2048 * 16 * 4;  // 8.4 MB
  float* Hin   = (float*)xn;   // 8.4 MB fits in dead xn (16.8 MB)
  u16*   ybf   = u_bf;         // u dead after conv; reuse for y

  // weight conversions
  f2bf_kernel<<<16384, 256, 0, stream>>>(in_proj_w,  w_in, 4096 * 1024);
  f2bf_kernel<<<768,   256, 0, stream>>>(x_proj_w,   w_xp, 96 * 2048);
  f2bf_kernel<<<512,   256, 0, stream>>>(dt_proj_w,  w_dt, 2048 * 64);
  f2bf_kernel<<<8192,  256, 0, stream>>>(out_proj_w, w_op, 1024 * 2048);

  // 1. layernorm -> bf16
  ln_kernel<<<8192, 256, 0, stream>>>(x, norm_w, norm_b, xn);
  // 2. in_proj: u/z bf16 halves = xn @ in_proj_w^T
  gemm_nt<128, 4, 3><<<dim3(64, 32), 256, 0, stream>>>(xn, w_in, u_bf, z_bf, nullptr, 1024, 4096);
  // 3. depthwise conv + SiLU -> bf16
  conv_kernel<<<8192, 256, 0, stream>>>(u_bf, conv_w, conv_b, ucbf);
  // 4. x_proj: xdbl[8192][96] = uc @ x_proj_w^T
  gemm_nt<96, 3, 0><<<dim3(64, 1), 256, 0, stream>>>(ucbf, w_xp, xdbl, nullptr, nullptr, 2048, 96);
  // 5. dt -> bf16
  dtbf_kernel<<<2048, 256, 0, stream>>>(xdbl, dtbf);
  // 6. dt_proj + bias + softplus -> bf16 delta[8192][2048]
  gemm_nt<128, 4, 1><<<dim3(64, 16), 256, 0, stream>>>(dtbf, w_dt, deltab, nullptr, dt_proj_b, 64, 2048);
  // 7. selective scan: chunk-parallel 3-pass
  scanA_kernel<<<dim3(8, 16, 4), 256, 0, stream>>>(deltab, ucbf, xdbl, A_log, Hc, Pc);
  scanB_kernel<<<512, 256, 0, stream>>>(Hc, Pc, Hin);
  scanC_kernel<<<dim3(8, 16, 4), 256, 0, stream>>>(deltab, ucbf, xdbl, z_bf, A_log, Dv, Hin, ybf);
  // 8. out_proj + residual: out[8192][1024] f32
  gemm_nt<128, 4, 2><<<dim3(64, 8), 256, 0, stream>>>(ybf, w_op, out, nullptr, x, 2048, 1024);
}

// Round 4
// 382.540 us; speedup vs baseline: 2.0555x; 1.0491x over previous
//
#include <hip/hip_runtime.h>
#include <stdint.h>

typedef unsigned short u16;
typedef unsigned int u32;
typedef __attribute__((ext_vector_type(8))) __bf16 bf16x8;
typedef __attribute__((ext_vector_type(4))) float f32x4;

#define DEV static __device__ __forceinline__

// ---------- small helpers ----------
DEV u16 f2bf(float f){
  u32 u = __float_as_uint(f);
  u += 0x7fffu + ((u >> 16) & 1u);   // round-to-nearest-even
  return (u16)(u >> 16);
}
DEV float bf2f(u16 h){ return __uint_as_float(((u32)h) << 16); }
DEV float exp2fast(float x){ return __builtin_amdgcn_exp2f(x); }
DEV float log2fast(float x){ return __builtin_amdgcn_logf(x); }
DEV float siluf(float x){ return x / (1.f + exp2fast(-1.44269504f * x)); }
DEV float softplusf(float x){
  if(x > 20.f) return x;
  return 0.69314718056f * log2fast(1.f + exp2fast(1.44269504f * x));
}

#define GLL(gp, lp) __builtin_amdgcn_global_load_lds( \
    (__attribute__((address_space(1))) void*)(gp),    \
    (__attribute__((address_space(3))) void*)(lp), 16, 0, 0)

#define VMCNT0 asm volatile("s_waitcnt vmcnt(0)" ::: "memory")
#define VMCNT1 asm volatile("s_waitcnt vmcnt(1)" ::: "memory")
#define VMCNT2 asm volatile("s_waitcnt vmcnt(2)" ::: "memory")
#define LGKM0  asm volatile("s_waitcnt lgkmcnt(0)" ::: "memory")
#define SCHEDB __builtin_amdgcn_sched_barrier(0)

// ---------- f32 -> bf16 conversion ----------
__global__ __launch_bounds__(256) void f2bf_kernel(const float* __restrict__ in,
                                                   u16* __restrict__ out, int n){
  int i = blockIdx.x * 256 + threadIdx.x;
  if(i < n) out[i] = f2bf(in[i]);
}

// ---------- LayerNorm (row=1024), writes bf16 ----------
__global__ __launch_bounds__(256) void ln_kernel(const float* __restrict__ x,
    const float* __restrict__ w, const float* __restrict__ bias,
    u16* __restrict__ xn){
  const int m = blockIdx.x;
  const int t = threadIdx.x;
  float4 v = ((const float4*)(x + (size_t)m * 1024))[t];
  float s  = v.x + v.y + v.z + v.w;
  float s2 = v.x*v.x + v.y*v.y + v.z*v.z + v.w*v.w;
#pragma unroll
  for(int o = 32; o; o >>= 1){ s += __shfl_xor(s, o); s2 += __shfl_xor(s2, o); }
  __shared__ float red[8];
  const int wv = t >> 6;
  if((t & 63) == 0){ red[wv] = s; red[4 + wv] = s2; }
  __syncthreads();
  s  = red[0] + red[1] + red[2] + red[3];
  s2 = red[4] + red[5] + red[6] + red[7];
  const float mu  = s * (1.f / 1024.f);
  const float var = s2 * (1.f / 1024.f) - mu * mu;
  const float rs  = rsqrtf(var + 1e-5f);
  float4 wv4 = ((const float4*)w)[t];
  float4 bv4 = ((const float4*)bias)[t];
  u32 o0 = (u32)f2bf((v.x - mu) * rs * wv4.x + bv4.x)
         | ((u32)f2bf((v.y - mu) * rs * wv4.y + bv4.y) << 16);
  u32 o1 = (u32)f2bf((v.z - mu) * rs * wv4.z + bv4.z)
         | ((u32)f2bf((v.w - mu) * rs * wv4.w + bv4.w) << 16);
  uint2 o = {o0, o1};
  ((uint2*)(xn + (size_t)m * 1024))[t] = o;
}

// ========== 256x256-tile 8-phase-style GEMM (in_proj) ==========
// C[M][4096] = A[M][K] * W[4096][K]^T, split-store bf16: col<2048->Cu else Cz.
// 8 waves (2M x 4N), per-wave 128x64. BK=32, LDS 64KB double-buffered.
// Stage order per K-tile (for tile t+1): p0:Bq01 p1:Bq23 p2:Aq02 p3:Aq13.
// Waits: vmcnt(2) end-of-p1 (guards cur tile's Aq13), vmcnt(1) end-of-p3
// (guards next tile's Bq01,Bq23,Aq02). LDS XOR-swizzle byte^=((row&3)<<4),
// applied to ds_read addr AND (inverse) to the global source column.
__global__ __launch_bounds__(512, 2) void gemm256(
    const u16* __restrict__ A, const u16* __restrict__ W,
    u16* __restrict__ Cu, u16* __restrict__ Cz, int K, int nby)
{
  __shared__ alignas(16) u16 lds[32768];   // [2 buf][A 16KB | B 16KB]
  const int tid = threadIdx.x;
  const int w = tid >> 6, lane = tid & 63;
  const int wm = w >> 2, wn = w & 3;
  const int lr = lane & 15, lg = lane >> 4;

  // XCD-aware bijective block swizzle (gridDim.x % 8 == 0)
  const int cpx = gridDim.x >> 3;
  const int bid = blockIdx.x;
  const int swz = (bid & 7) * cpx + (bid >> 3);
  const int bx = swz / nby, by = swz % nby;
  const int m0 = bx * 256, n0 = by * 256;

  // staging thread-constants (source col pre-swizzled: involution of read swz)
  const int col_e = 8 * ((tid & 3) ^ ((tid >> 2) & 3));
  const int sub   = tid & 255;
  const u16* Bsrc = W + (size_t)(n0 + (tid >> 2)) * K + col_e;
  const u16* Asrc = A + (size_t)(m0 + ((tid >> 8) << 7) + (sub >> 2)) * K + col_e;
  char* ldsc = (char*)lds;
  const int adst = ((tid >> 8) << 13) + sub * 16;   // Aq02 dest (Aq13: +4096)
  const int bdst = tid * 16;                        // Bq01 dest (Bq23: +8192)

  f32x4 acc[8][4];
  const f32x4 z4 = {0.f, 0.f, 0.f, 0.f};
#pragma unroll
  for(int i = 0; i < 8; i++)
#pragma unroll
    for(int j = 0; j < 4; j++) acc[i][j] = z4;

  // prologue: stage tile 0 into buf0
  GLL(Bsrc,                 ldsc + 16384 + bdst);
  GLL(Bsrc + (size_t)128*K, ldsc + 16384 + 8192 + bdst);
  GLL(Asrc,                 ldsc + adst);
  GLL(Asrc + (size_t)64*K,  ldsc + 4096 + adst);
  VMCNT1;
  __builtin_amdgcn_s_barrier();

  const int NT = K >> 5;
  const int swr = (lr & 3);               // row-dependent swizzle bits
  for(int t = 0; t < NT; ++t){
    const int cb = (t & 1) << 15;
    const int nb = cb ^ 32768;
    const char* Ab = ldsc + cb;
    const char* Bb = ldsc + cb + 16384;
    const bool stg = (t + 1) < NT;
    const int kk = (t + 1) << 5;
    bf16x8 afr[4], bfr[4];

    // ---------- phase 0: A fm0-3 + B fn0-1 reads; stage Bq01(t+1)
#pragma unroll
    for(int i = 0; i < 4; i++){
      int r = wm * 128 + i * 16 + lr;
      afr[i] = *(const bf16x8*)(Ab + r * 64 + ((lg ^ swr) << 4));
    }
#pragma unroll
    for(int jn = 0; jn < 2; jn++){
      int r = wn * 64 + jn * 16 + lr;
      bfr[jn] = *(const bf16x8*)(Bb + r * 64 + ((lg ^ swr) << 4));
    }
    if(stg){ GLL(Bsrc + kk, ldsc + nb + 16384 + bdst); }
    SCHEDB; __builtin_amdgcn_s_barrier();
    LGKM0; SCHEDB;
    __builtin_amdgcn_s_setprio(1);
#pragma unroll
    for(int i = 0; i < 4; i++)
#pragma unroll
      for(int jn = 0; jn < 2; jn++)
        acc[i][jn] = __builtin_amdgcn_mfma_f32_16x16x32_bf16(afr[i], bfr[jn], acc[i][jn], 0, 0, 0);
    __builtin_amdgcn_s_setprio(0);
    SCHEDB; __builtin_amdgcn_s_barrier();

    // ---------- phase 1: B fn2-3 reads; stage Bq23(t+1); vmcnt guards Aq13(t)
#pragma unroll
    for(int jn = 2; jn < 4; jn++){
      int r = wn * 64 + jn * 16 + lr;
      bfr[jn] = *(const bf16x8*)(Bb + r * 64 + ((lg ^ swr) << 4));
    }
    if(stg){ GLL(Bsrc + (size_t)128*K + kk, ldsc + nb + 16384 + 8192 + bdst); }
    SCHEDB; __builtin_amdgcn_s_barrier();
    LGKM0; SCHEDB;
    __builtin_amdgcn_s_setprio(1);
#pragma unroll
    for(int i = 0; i < 4; i++)
#pragma unroll
      for(int jn = 2; jn < 4; jn++)
        acc[i][jn] = __builtin_amdgcn_mfma_f32_16x16x32_bf16(afr[i], bfr[jn], acc[i][jn], 0, 0, 0);
    __builtin_amdgcn_s_setprio(0);
    if(stg){ VMCNT2; } else { VMCNT0; }
    SCHEDB; __builtin_amdgcn_s_barrier();

    // ---------- phase 2: A fm4-7 reads; stage Aq02(t+1)
#pragma unroll
    for(int i = 0; i < 4; i++){
      int r = wm * 128 + 64 + i * 16 + lr;
      afr[i] = *(const bf16x8*)(Ab + r * 64 + ((lg ^ swr) << 4));
    }
    if(stg){ GLL(Asrc + kk, ldsc + nb + adst); }
    SCHEDB; __builtin_amdgcn_s_barrier();
    LGKM0; SCHEDB;
    __builtin_amdgcn_s_setprio(1);
#pragma unroll
    for(int i = 0; i < 4; i++)
#pragma unroll
      for(int jn = 0; jn < 2; jn++)
        acc[4 + i][jn] = __builtin_amdgcn_mfma_f32_16x16x32_bf16(afr[i], bfr[jn], acc[4 + i][jn], 0, 0, 0);
    __builtin_amdgcn_s_setprio(0);
    SCHEDB; __builtin_amdgcn_s_barrier();

    // ---------- phase 3: stage Aq13(t+1); vmcnt(1) leaves it in flight
    if(stg){ GLL(Asrc + (size_t)64*K + kk, ldsc + nb + 4096 + adst); }
    SCHEDB; __builtin_amdgcn_s_barrier();
    __builtin_amdgcn_s_setprio(1);
#pragma unroll
    for(int i = 0; i < 4; i++)
#pragma unroll
      for(int jn = 2; jn < 4; jn++)
        acc[4 + i][jn] = __builtin_amdgcn_mfma_f32_16x16x32_bf16(afr[i], bfr[jn], acc[4 + i][jn], 0, 0, 0);
    __builtin_amdgcn_s_setprio(0);
    if(stg){ VMCNT1; }
    SCHEDB; __builtin_amdgcn_s_barrier();
  }

  // epilogue: split bf16 store (u | z)
#pragma unroll
  for(int fm = 0; fm < 8; fm++){
#pragma unroll
    for(int fn = 0; fn < 4; fn++){
      int cc = n0 + wn * 64 + fn * 16 + lr;
      int r0 = m0 + wm * 128 + fm * 16 + lg * 4;
#pragma unroll
      for(int j = 0; j < 4; j++){
        float v = acc[fm][fn][j];
        size_t rr = r0 + j;
        if(cc < 2048) Cu[rr * 2048 + cc] = f2bf(v);
        else          Cz[rr * 2048 + (cc - 2048)] = f2bf(v);
      }
    }
  }
}

// ---------- bf16 MFMA GEMM:  C[M][N] = A[M][K] * W[N][K]^T  (NT) ----------
// 128 x BN tile, BK=32, 4 waves as 2x2, each wave 64 x (BN/2).
// EPI: 1 = bf16 store of softplus(acc + ep[n])   (dt_proj -> delta)
//      2 = f32 store of acc + ep[m*ldc+n]        (out_proj + residual)
template<int BN, int FN, int EPI>
__global__ __launch_bounds__(256) void gemm_nt(
    const u16* __restrict__ A, const u16* __restrict__ W,
    void* __restrict__ Cv, void* __restrict__ C2v,
    const float* __restrict__ ep, int K, int ldc)
{
  constexpr int WN   = BN / 2;
  constexpr int NCHB = (BN * 64) / 1024;
  __shared__ alignas(16) u16 As[128 * 32];
  __shared__ alignas(16) u16 Bs[BN * 32];

  const int tid  = threadIdx.x;
  const int wave = tid >> 6, lane = tid & 63;
  const int wm = wave >> 1, wn = wave & 1;
  const int lr = lane & 15, lg = lane >> 4;
  const int m0 = blockIdx.x * 128, n0 = blockIdx.y * BN;

  f32x4 acc[4][FN];
  const f32x4 z4 = {0.f, 0.f, 0.f, 0.f};
#pragma unroll
  for(int i = 0; i < 4; i++)
#pragma unroll
    for(int j = 0; j < FN; j++) acc[i][j] = z4;

  for(int k0 = 0; k0 < K; k0 += 32){
#pragma unroll
    for(int i = 0; i < 2; i++){
      int off = (wave + 4 * i) * 1024 + lane * 16;
      int row = off >> 6, cbyte = off & 63;
      GLL(A + (size_t)(m0 + row) * K + k0 + (cbyte >> 1), (char*)As + off);
    }
    for(int ch = wave; ch < NCHB; ch += 4){
      int off = ch * 1024 + lane * 16;
      int row = off >> 6, cbyte = off & 63;
      GLL(W + (size_t)(n0 + row) * K + k0 + (cbyte >> 1), (char*)Bs + off);
    }
    __syncthreads();

    bf16x8 af[4], bfr[FN];
#pragma unroll
    for(int fm = 0; fm < 4; fm++)
      af[fm] = *(const bf16x8*)(As + (wm * 64 + fm * 16 + lr) * 32 + lg * 8);
#pragma unroll
    for(int fn = 0; fn < FN; fn++)
      bfr[fn] = *(const bf16x8*)(Bs + (wn * WN + fn * 16 + lr) * 32 + lg * 8);
#pragma unroll
    for(int fm = 0; fm < 4; fm++)
#pragma unroll
      for(int fn = 0; fn < FN; fn++)
        acc[fm][fn] = __builtin_amdgcn_mfma_f32_16x16x32_bf16(af[fm], bfr[fn], acc[fm][fn], 0, 0, 0);
    __syncthreads();
  }

#pragma unroll
  for(int fm = 0; fm < 4; fm++){
#pragma unroll
    for(int fn = 0; fn < FN; fn++){
      int cc = n0 + wn * WN + fn * 16 + lr;
      int r0 = m0 + wm * 64 + fm * 16 + lg * 4;
      f32x4 a = acc[fm][fn];
#pragma unroll
      for(int j = 0; j < 4; j++){
        float v = a[j];
        int r = r0 + j;
        size_t idx = (size_t)r * ldc + cc;
        if constexpr(EPI == 1){
          ((u16*)Cv)[idx] = f2bf(softplusf(v + ep[cc]));
        } else {
          ((float*)Cv)[idx] = v + ep[idx];
        }
      }
    }
  }
}

// ---------- x_proj GEMM: 32x96 tile, 256 blocks; fused dt->bf16 + bc f32 ----
__global__ __launch_bounds__(256) void gemm_xp(
    const u16* __restrict__ A, const u16* __restrict__ W,
    u16* __restrict__ dtb, float* __restrict__ bc, int K)
{
  __shared__ alignas(16) u16 ABs[4096];   // 32 A-rows + 96 B-rows, 32 cols
  const int tid  = threadIdx.x;
  const int wave = tid >> 6, lane = tid & 63;
  const int wm = wave >> 1, wn = wave & 1;
  const int lr = lane & 15, lg = lane >> 4;
  const int m0 = blockIdx.x * 32;

  f32x4 acc[3];
  const f32x4 z4 = {0.f, 0.f, 0.f, 0.f};
#pragma unroll
  for(int j = 0; j < 3; j++) acc[j] = z4;

  for(int k0 = 0; k0 < K; k0 += 32){
#pragma unroll
    for(int i = 0; i < 2; i++){
      int off = tid * 16 + i * 4096;
      int row = off >> 6, cb = off & 63;
      const u16* src = (row < 32)
        ? A + (size_t)(m0 + row) * K + k0 + (cb >> 1)
        : W + (size_t)(row - 32) * K + k0 + (cb >> 1);
      GLL(src, (char*)ABs + off);
    }
    __syncthreads();
    bf16x8 af = *(const bf16x8*)(ABs + (wm * 16 + lr) * 32 + lg * 8);
    bf16x8 bfr[3];
#pragma unroll
    for(int fn = 0; fn < 3; fn++)
      bfr[fn] = *(const bf16x8*)(ABs + (32 + wn * 48 + fn * 16 + lr) * 32 + lg * 8);
#pragma unroll
    for(int fn = 0; fn < 3; fn++)
      acc[fn] = __builtin_amdgcn_mfma_f32_16x16x32_bf16(af, bfr[fn], acc[fn], 0, 0, 0);
    __syncthreads();
  }

#pragma unroll
  for(int fn = 0; fn < 3; fn++){
    int cc = wn * 48 + fn * 16 + lr;
    int r0 = m0 + wm * 16 + lg * 4;
#pragma unroll
    for(int j = 0; j < 4; j++){
      float v = acc[fn][j];
      size_t rr = r0 + j;
      if(cc < 64) dtb[rr * 64 + cc] = f2bf(v);
      else        bc[rr * 32 + (cc - 64)] = v;
    }
  }
}

// ---------- depthwise causal conv (k=4) + bias + SiLU, bf16 in/out ----------
__global__ __launch_bounds__(256) void conv_kernel(
    const u16* __restrict__ ub, const float* __restrict__ cw,
    const float* __restrict__ cb, u16* __restrict__ uc)
{
  const int m = blockIdx.x;
  const int l = m & 2047;
  const int d0 = threadIdx.x * 8;
  float4 w4[8];
#pragma unroll
  for(int i = 0; i < 8; i++) w4[i] = *(const float4*)(cw + (size_t)(d0 + i) * 4);
  float r[4][8];
#pragma unroll
  for(int j = 0; j < 4; j++)
#pragma unroll
    for(int i = 0; i < 8; i++) r[j][i] = 0.f;
  for(int j = 0; j < 4; j++){
    if(l - 3 + j < 0) continue;
    uint4 a = *(const uint4*)(ub + (size_t)(m - 3 + j) * 2048 + d0);
    u32 w0 = a.x, w1 = a.y, w2 = a.z, w3 = a.w;
    r[j][0] = bf2f((u16)(w0 & 0xffff)); r[j][1] = bf2f((u16)(w0 >> 16));
    r[j][2] = bf2f((u16)(w1 & 0xffff)); r[j][3] = bf2f((u16)(w1 >> 16));
    r[j][4] = bf2f((u16)(w2 & 0xffff)); r[j][5] = bf2f((u16)(w2 >> 16));
    r[j][6] = bf2f((u16)(w3 & 0xffff)); r[j][7] = bf2f((u16)(w3 >> 16));
  }
  float4 b0 = *(const float4*)(cb + d0), b1 = *(const float4*)(cb + d0 + 4);
  float bb[8] = {b0.x, b0.y, b0.z, b0.w, b1.x, b1.y, b1.z, b1.w};
  u32 outw[4];
#pragma unroll
  for(int i = 0; i < 4; i++){
    int e0 = 2 * i, e1 = 2 * i + 1;
    float v0 = bb[e0] + r[0][e0]*w4[e0].x + r[1][e0]*w4[e0].y + r[2][e0]*w4[e0].z + r[3][e0]*w4[e0].w;
    float v1 = bb[e1] + r[0][e1]*w4[e1].x + r[1][e1]*w4[e1].y + r[2][e1]*w4[e1].z + r[3][e1]*w4[e1].w;
    outw[i] = (u32)f2bf(siluf(v0)) | ((u32)f2bf(siluf(v1)) << 16);
  }
  uint4 o = {outw[0], outw[1], outw[2], outw[3]};
  *(uint4*)(uc + (size_t)m * 2048 + d0) = o;
}

// ================= selective scan: chunk-parallel, 1 lane = 1 channel ======
__global__ __launch_bounds__(256) void scanA_kernel(
    const u16* __restrict__ deltab, const u16* __restrict__ uc,
    const float* __restrict__ bc, const float* __restrict__ A_log,
    float* __restrict__ Hc, float* __restrict__ Pc)
{
  __shared__ u16   sd[16][256];
  __shared__ u16   su[16][256];
  __shared__ float sB[16][16];
  const int tid = threadIdx.x;
  const int dg = blockIdx.x, chunk = blockIdx.y, b = blockIdx.z;
  const int d  = dg * 256 + tid;

  float a2[16], h[16], P[16];
#pragma unroll
  for(int q = 0; q < 4; q++){
    float4 al = *(const float4*)(A_log + (size_t)d * 16 + q * 4);
    a2[q*4+0] = -expf(al.x) * 1.44269504f;
    a2[q*4+1] = -expf(al.y) * 1.44269504f;
    a2[q*4+2] = -expf(al.z) * 1.44269504f;
    a2[q*4+3] = -expf(al.w) * 1.44269504f;
  }
#pragma unroll
  for(int s = 0; s < 16; s++){ h[s] = 0.f; P[s] = 1.f; }

  for(int w = 0; w < 8; w++){
    const size_t m0 = (size_t)b * 2048 + chunk * 128 + w * 16;
#pragma unroll
    for(int i = 0; i < 2; i++){
      int fo = tid + i * 256;
      int row = fo >> 5, col = (fo & 31) * 8;
      *(uint4*)&sd[row][col] = *(const uint4*)(deltab + (m0 + row) * 2048 + dg * 256 + col);
      *(uint4*)&su[row][col] = *(const uint4*)(uc     + (m0 + row) * 2048 + dg * 256 + col);
    }
    if(tid < 64){
      int row = tid >> 2, col = (tid & 3) * 4;
      *(float4*)&sB[row][col] = *(const float4*)(bc + (m0 + row) * 32 + col);
    }
    __syncthreads();
#pragma unroll 2
    for(int l = 0; l < 16; l++){
      float dt = bf2f(sd[l][tid]);
      float u  = bf2f(su[l][tid]);
      float du = dt * u;
      float4 B0 = *(const float4*)&sB[l][0];
      float4 B1 = *(const float4*)&sB[l][4];
      float4 B2 = *(const float4*)&sB[l][8];
      float4 B3 = *(const float4*)&sB[l][12];
      float Bv[16] = {B0.x,B0.y,B0.z,B0.w,B1.x,B1.y,B1.z,B1.w,
                      B2.x,B2.y,B2.z,B2.w,B3.x,B3.y,B3.z,B3.w};
#pragma unroll
      for(int s = 0; s < 16; s++){
        float e = exp2fast(dt * a2[s]);
        P[s] *= e;
        h[s] = __builtin_fmaf(e, h[s], du * Bv[s]);
      }
    }
    __syncthreads();
  }
  const size_t base = (((size_t)b * 16 + chunk) * 2048 + d) * 16;
#pragma unroll
  for(int q = 0; q < 4; q++){
    float4 hv = {h[q*4], h[q*4+1], h[q*4+2], h[q*4+3]};
    float4 pv = {P[q*4], P[q*4+1], P[q*4+2], P[q*4+3]};
    *(float4*)(Hc + base + q * 4) = hv;
    *(float4*)(Pc + base + q * 4) = pv;
  }
}

__global__ __launch_bounds__(256) void scanB_kernel(
    const float* __restrict__ Hc, const float* __restrict__ Pc,
    float* __restrict__ Hin)
{
  const int e = blockIdx.x * 256 + threadIdx.x;
  const int b = e >> 15, rem = e & 32767;
  float hin = 0.f;
  for(int c = 0; c < 16; c++){
    size_t idx = (((size_t)b * 16 + c) << 15) + rem;
    Hin[idx] = hin;
    hin = __builtin_fmaf(Pc[idx], hin, Hc[idx]);
  }
}

__global__ __launch_bounds__(256) void scanC_kernel(
    const u16* __restrict__ deltab, const u16* __restrict__ uc,
    const float* __restrict__ bc, const u16* __restrict__ zb,
    const float* __restrict__ A_log, const float* __restrict__ Dv,
    const float* __restrict__ Hin, u16* __restrict__ ybf)
{
  __shared__ u16   sd[16][256];
  __shared__ u16   su[16][256];
  __shared__ u16   sz[16][256];
  __shared__ float sBC[16][32];
  __shared__ u16   sy[16][256];
  const int tid = threadIdx.x;
  const int dg = blockIdx.x, chunk = blockIdx.y, b = blockIdx.z;
  const int d  = dg * 256 + tid;

  float a2[16], h[16];
#pragma unroll
  for(int q = 0; q < 4; q++){
    float4 al = *(const float4*)(A_log + (size_t)d * 16 + q * 4);
    a2[q*4+0] = -expf(al.x) * 1.44269504f;
    a2[q*4+1] = -expf(al.y) * 1.44269504f;
    a2[q*4+2] = -expf(al.z) * 1.44269504f;
    a2[q*4+3] = -expf(al.w) * 1.44269504f;
  }
  const size_t hbase = (((size_t)b * 16 + chunk) * 2048 + d) * 16;
#pragma unroll
  for(int q = 0; q < 4; q++){
    float4 hv = *(const float4*)(Hin + hbase + q * 4);
    h[q*4] = hv.x; h[q*4+1] = hv.y; h[q*4+2] = hv.z; h[q*4+3] = hv.w;
  }
  const float Dd = Dv[d];

  for(int w = 0; w < 8; w++){
    const size_t m0 = (size_t)b * 2048 + chunk * 128 + w * 16;
#pragma unroll
    for(int i = 0; i < 2; i++){
      int fo = tid + i * 256;
      int row = fo >> 5, col = (fo & 31) * 8;
      *(uint4*)&sd[row][col] = *(const uint4*)(deltab + (m0 + row) * 2048 + dg * 256 + col);
      *(uint4*)&su[row][col] = *(const uint4*)(uc     + (m0 + row) * 2048 + dg * 256 + col);
      *(uint4*)&sz[row][col] = *(const uint4*)(zb     + (m0 + row) * 2048 + dg * 256 + col);
    }
    if(tid < 128){
      int row = tid >> 3, col = (tid & 7) * 4;
      *(float4*)&sBC[row][col] = *(const float4*)(bc + (m0 + row) * 32 + col);
    }
    __syncthreads();
#pragma unroll 2
    for(int l = 0; l < 16; l++){
      float dt = bf2f(sd[l][tid]);
      float u  = bf2f(su[l][tid]);
      float du = dt * u;
      float4 B0 = *(const float4*)&sBC[l][0];
      float4 B1 = *(const float4*)&sBC[l][4];
      float4 B2 = *(const float4*)&sBC[l][8];
      float4 B3 = *(const float4*)&sBC[l][12];
      float4 C0 = *(const float4*)&sBC[l][16];
      float4 C1 = *(const float4*)&sBC[l][20];
      float4 C2 = *(const float4*)&sBC[l][24];
      float4 C3 = *(const float4*)&sBC[l][28];
      float Bv[16] = {B0.x,B0.y,B0.z,B0.w,B1.x,B1.y,B1.z,B1.w,
                      B2.x,B2.y,B2.z,B2.w,B3.x,B3.y,B3.z,B3.w};
      float Cv[16] = {C0.x,C0.y,C0.z,C0.w,C1.x,C1.y,C1.z,C1.w,
                      C2.x,C2.y,C2.z,C2.w,C3.x,C3.y,C3.z,C3.w};
      float y = 0.f;
#pragma unroll
      for(int s = 0; s < 16; s++){
        float e = exp2fast(dt * a2[s]);
        h[s] = __builtin_fmaf(e, h[s], du * Bv[s]);
        y = __builtin_fmaf(h[s], Cv[s], y);
      }
      float z = bf2f(sz[l][tid]);
      y = (y + Dd * u) * siluf(z);
      sy[l][tid] = f2bf(y);
    }
    __syncthreads();
#pragma unroll
    for(int i = 0; i < 2; i++){
      int fo = tid + i * 256;
      int row = fo >> 5, col = (fo & 31) * 8;
      *(uint4*)(ybf + (m0 + row) * 2048 + dg * 256 + col) = *(const uint4*)&sy[row][col];
    }
  }
}

// ---------- launch ----------
extern "C" void kernel_launch(void* const* d_in, const int* in_sizes, int n_in,
                              void* d_out, int out_size, void* d_ws, size_t ws_size,
                              hipStream_t stream) {
  (void)in_sizes; (void)n_in; (void)out_size; (void)ws_size;
  const float* x         = (const float*)d_in[0];
  const float* norm_w    = (const float*)d_in[1];
  const float* norm_b    = (const float*)d_in[2];
  const float* in_proj_w = (const float*)d_in[3];
  const float* conv_w    = (const float*)d_in[4];
  const float* conv_b    = (const float*)d_in[5];
  const float* x_proj_w  = (const float*)d_in[6];
  const float* dt_proj_w = (const float*)d_in[7];
  const float* dt_proj_b = (const float*)d_in[8];
  const float* A_log     = (const float*)d_in[9];
  const float* Dv        = (const float*)d_in[10];
  const float* out_proj_w= (const float*)d_in[11];
  float* out = (float*)d_out;

  // workspace layout (~183 MB total)
  char* ws = (char*)d_ws;
  u16*   w_in  = (u16*)ws;  ws += (size_t)4096 * 1024 * 2;
  u16*   w_xp  = (u16*)ws;  ws += (size_t)96 * 2048 * 2;
  u16*   w_dt  = (u16*)ws;  ws += (size_t)2048 * 64 * 2;
  u16*   w_op  = (u16*)ws;  ws += (size_t)1024 * 2048 * 2;
  u16*   xn    = (u16*)ws;  ws += (size_t)8192 * 1024 * 2;
  u16*   u_bf  = (u16*)ws;  ws += (size_t)8192 * 2048 * 2;
  u16*   z_bf  = (u16*)ws;  ws += (size_t)8192 * 2048 * 2;
  u16*   ucbf  = (u16*)ws;  ws += (size_t)8192 * 2048 * 2;
  float* bc    = (float*)ws; ws += (size_t)8192 * 32 * 4;
  u16*   dtbf  = (u16*)ws;  ws += (size_t)8192 * 64 * 2;
  u16*   deltab= (u16*)ws;  ws += (size_t)8192 * 2048 * 2;
  float* Hc    = (float*)ws; ws += (size_t)4 * 16 * 2048 * 16 * 4;
  float* Pc    = (float*)ws; ws += (size_t)4 * 16 * 2048 * 16 * 4;
  float* Hin   = (float*)xn;   // dead after in_proj
  u16*   ybf   = u_bf;         // u dead after conv

  // weight conversions
  f2bf_kernel<<<16384, 256, 0, stream>>>(in_proj_w,  w_in, 4096 * 1024);
  f2bf_kernel<<<768,   256, 0, stream>>>(x_proj_w,   w_xp, 96 * 2048);
  f2bf_kernel<<<512,   256, 0, stream>>>(dt_proj_w,  w_dt, 2048 * 64);
  f2bf_kernel<<<8192,  256, 0, stream>>>(out_proj_w, w_op, 1024 * 2048);

  // 1. layernorm -> bf16
  ln_kernel<<<8192, 256, 0, stream>>>(x, norm_w, norm_b, xn);
  // 2. in_proj (256x256 8-phase): u/z bf16 halves
  gemm256<<<512, 512, 0, stream>>>(xn, w_in, u_bf, z_bf, 1024, 16);
  // 3. depthwise conv + SiLU -> bf16
  conv_kernel<<<8192, 256, 0, stream>>>(u_bf, conv_w, conv_b, ucbf);
  // 4. x_proj fused: dt->bf16, B/C -> bc f32
  gemm_xp<<<256, 256, 0, stream>>>(ucbf, w_xp, dtbf, bc, 2048);
  // 5. dt_proj + bias + softplus -> bf16 delta
  gemm_nt<128, 4, 1><<<dim3(64, 16), 256, 0, stream>>>(dtbf, w_dt, deltab, nullptr, dt_proj_b, 64, 2048);
  // 6. selective scan: chunk-parallel 3-pass
  scanA_kernel<<<dim3(8, 16, 4), 256, 0, stream>>>(deltab, ucbf, bc, A_log, Hc, Pc);
  scanB_kernel<<<512, 256, 0, stream>>>(Hc, Pc, Hin);
  scanC_kernel<<<dim3(8, 16, 4), 256, 0, stream>>>(deltab, ucbf, bc, z_bf, A_log, Dv, Hin, ybf);
  // 7. out_proj + residual
  gemm_nt<128, 4, 2><<<dim3(64, 8), 256, 0, stream>>>(ybf, w_op, out, nullptr, x, 2048, 1024);
}

// Round 5
// 374.745 us; speedup vs baseline: 2.0983x; 1.0208x over previous
//
#include <hip/hip_runtime.h>
#include <stdint.h>

typedef unsigned short u16;
typedef unsigned int u32;
typedef __attribute__((ext_vector_type(8))) __bf16 bf16x8;
typedef __attribute__((ext_vector_type(4))) float f32x4;

#define DEV static __device__ __forceinline__

// ---------- small helpers ----------
DEV u16 f2bf(float f){
  u32 u = __float_as_uint(f);
  u += 0x7fffu + ((u >> 16) & 1u);   // round-to-nearest-even
  return (u16)(u >> 16);
}
DEV float bf2f(u16 h){ return __uint_as_float(((u32)h) << 16); }
DEV float exp2fast(float x){ return __builtin_amdgcn_exp2f(x); }
DEV float log2fast(float x){ return __builtin_amdgcn_logf(x); }
DEV float siluf(float x){ return x / (1.f + exp2fast(-1.44269504f * x)); }
DEV float softplusf(float x){
  if(x > 20.f) return x;
  return 0.69314718056f * log2fast(1.f + exp2fast(1.44269504f * x));
}

#define GLL(gp, lp) __builtin_amdgcn_global_load_lds( \
    (__attribute__((address_space(1))) void*)(gp),    \
    (__attribute__((address_space(3))) void*)(lp), 16, 0, 0)

#define VMCNT0 asm volatile("s_waitcnt vmcnt(0)" ::: "memory")
#define VMCNT2 asm volatile("s_waitcnt vmcnt(2)" ::: "memory")
#define VMCNT4 asm volatile("s_waitcnt vmcnt(4)" ::: "memory")
#define LGKM0  asm volatile("s_waitcnt lgkmcnt(0)" ::: "memory")
#define SCHEDB __builtin_amdgcn_sched_barrier(0)

// ---------- f32 -> bf16 conversion ----------
__global__ __launch_bounds__(256) void f2bf_kernel(const float* __restrict__ in,
                                                   u16* __restrict__ out, int n){
  int i = blockIdx.x * 256 + threadIdx.x;
  if(i < n) out[i] = f2bf(in[i]);
}

// ---------- LayerNorm (row=1024), writes bf16 ----------
__global__ __launch_bounds__(256) void ln_kernel(const float* __restrict__ x,
    const float* __restrict__ w, const float* __restrict__ bias,
    u16* __restrict__ xn){
  const int m = blockIdx.x;
  const int t = threadIdx.x;
  float4 v = ((const float4*)(x + (size_t)m * 1024))[t];
  float s  = v.x + v.y + v.z + v.w;
  float s2 = v.x*v.x + v.y*v.y + v.z*v.z + v.w*v.w;
#pragma unroll
  for(int o = 32; o; o >>= 1){ s += __shfl_xor(s, o); s2 += __shfl_xor(s2, o); }
  __shared__ float red[8];
  const int wv = t >> 6;
  if((t & 63) == 0){ red[wv] = s; red[4 + wv] = s2; }
  __syncthreads();
  s  = red[0] + red[1] + red[2] + red[3];
  s2 = red[4] + red[5] + red[6] + red[7];
  const float mu  = s * (1.f / 1024.f);
  const float var = s2 * (1.f / 1024.f) - mu * mu;
  const float rs  = rsqrtf(var + 1e-5f);
  float4 wv4 = ((const float4*)w)[t];
  float4 bv4 = ((const float4*)bias)[t];
  u32 o0 = (u32)f2bf((v.x - mu) * rs * wv4.x + bv4.x)
         | ((u32)f2bf((v.y - mu) * rs * wv4.y + bv4.y) << 16);
  u32 o1 = (u32)f2bf((v.z - mu) * rs * wv4.z + bv4.z)
         | ((u32)f2bf((v.w - mu) * rs * wv4.w + bv4.w) << 16);
  uint2 o = {o0, o1};
  ((uint2*)(xn + (size_t)m * 1024))[t] = o;
}

// ========== 256x256-tile BK=64 4-phase GEMM (in_proj) ==========
// C[M][4096] = A[M][K] * W[4096][K]^T, split bf16 store: col<2048->Cu else Cz.
// 8 waves (2M x 4N), per-wave 128x64. LDS 128KB: 2 bufs x (A 32KB | B 32KB).
// Rows are 128B (64 bf16). Swizzle: LDS[row][chunk] = glob[row][chunk^(row&7)]
// (16B chunks); read chunk = (kk*4+lg)^(row&7). 16-lane group -> 2 lanes/quad.
// Staging: 8 sweeps/tile (8KB each), 2 per phase, for tile t+1:
//   p0: B0,B1   p1: B2,B3   p2: A0,A2   p3: A1,A3
// Ledger waits (before phase-final barrier):
//   end-p1: vmcnt(4)  -- drains A1,A3 of tile t (issued t-1 p3)
//   end-p3: vmcnt(2)  -- drains B0..B3,A0,A2 of t+1; leaves A1,A3 in flight
// Last tile: vmcnt(0) at end-p1 (nothing new issued).
__global__ __launch_bounds__(512, 2) void gemm256(
    const u16* __restrict__ A, const u16* __restrict__ W,
    u16* __restrict__ Cu, u16* __restrict__ Cz, int K, int nby)
{
  __shared__ alignas(16) u16 lds[65536];   // 128KB
  const int tid = threadIdx.x;
  const int w = tid >> 6, lane = tid & 63;
  const int wm = w >> 2, wn = w & 3;
  const int lr = lane & 15, lg = lane >> 4;

  // XCD-aware bijective block swizzle (gridDim.x % 8 == 0)
  const int cpx = gridDim.x >> 3;
  const int bid = blockIdx.x;
  const int swz = (bid & 7) * cpx + (bid >> 3);
  const int bx = swz / nby, by = swz % nby;
  const int m0 = bx * 256, n0 = by * 256;

  // staging constants: sweep = 64 rows x 128B; thread -> row tid>>3, chunk tid&7
  const int srow = tid >> 3;
  const int scol = 8 * ((tid & 7) ^ (srow & 7));   // pre-swizzled source chunk
  const u16* Asw = A + (size_t)(m0 + srow) * K + scol;
  const u16* Bsw = W + (size_t)(n0 + srow) * K + scol;
  char* ldsc = (char*)lds;
  const int sdst = tid * 16;

  // read swizzle: chunk = (kk*4+lg) ^ (lr&7); row&7 == lr&7 for all frags
  const int cx0 = (lg ^ (lr & 7)) << 4;
  const int cx1 = cx0 ^ 64;

  f32x4 acc[8][4];
  const f32x4 z4 = {0.f, 0.f, 0.f, 0.f};
#pragma unroll
  for(int i = 0; i < 8; i++)
#pragma unroll
    for(int j = 0; j < 4; j++) acc[i][j] = z4;

  // prologue: stage tile 0 into buf0, order B0..B3,A0,A2,A1,A3
  GLL(Bsw,                  ldsc + 32768 + sdst);
  GLL(Bsw + (size_t)64*K,   ldsc + 32768 + 8192 + sdst);
  GLL(Bsw + (size_t)128*K,  ldsc + 32768 + 16384 + sdst);
  GLL(Bsw + (size_t)192*K,  ldsc + 32768 + 24576 + sdst);
  GLL(Asw,                  ldsc + sdst);
  GLL(Asw + (size_t)128*K,  ldsc + 16384 + sdst);
  GLL(Asw + (size_t)64*K,   ldsc + 8192 + sdst);
  GLL(Asw + (size_t)192*K,  ldsc + 24576 + sdst);
  VMCNT2;
  __builtin_amdgcn_s_barrier();

  const int NT = K >> 6;
  for(int t = 0; t < NT; ++t){
    const int cb = (t & 1) << 17;          // byte offset: 131072 per buffer? no:
    // NOTE: buffers are 64KB each -> byte offsets 0 / 65536
    const int cbo = (t & 1) * 65536;
    const int nbo = cbo ^ 65536;
    const char* Ab = ldsc + cbo;
    const char* Bb = ldsc + cbo + 32768;
    char* nbc = ldsc + nbo;
    const bool stg = (t + 1) < NT;
    const int koff = (t + 1) << 6;
    (void)cb;
    bf16x8 afr[4], bf0[4], bf1[4];

    // ---------- phase 0: Mlo k0 + B k0 reads; stage B0,B1(t+1)
#pragma unroll
    for(int i = 0; i < 4; i++)
      afr[i] = *(const bf16x8*)(Ab + (wm*128 + i*16 + lr)*128 + cx0);
#pragma unroll
    for(int j = 0; j < 4; j++)
      bf0[j] = *(const bf16x8*)(Bb + (wn*64 + j*16 + lr)*128 + cx0);
    if(stg){
      GLL(Bsw + koff,                 nbc + 32768 + sdst);
      GLL(Bsw + (size_t)64*K + koff, nbc + 32768 + 8192 + sdst);
    }
    SCHEDB; __builtin_amdgcn_s_barrier();
    LGKM0; SCHEDB;
    __builtin_amdgcn_s_setprio(1);
#pragma unroll
    for(int i = 0; i < 4; i++)
#pragma unroll
      for(int j = 0; j < 4; j++)
        acc[i][j] = __builtin_amdgcn_mfma_f32_16x16x32_bf16(afr[i], bf0[j], acc[i][j], 0, 0, 0);
    __builtin_amdgcn_s_setprio(0);
    SCHEDB; __builtin_amdgcn_s_barrier();

    // ---------- phase 1: Mlo k1 + B k1 reads; stage B2,B3(t+1); vmcnt(4)
#pragma unroll
    for(int i = 0; i < 4; i++)
      afr[i] = *(const bf16x8*)(Ab + (wm*128 + i*16 + lr)*128 + cx1);
#pragma unroll
    for(int j = 0; j < 4; j++)
      bf1[j] = *(const bf16x8*)(Bb + (wn*64 + j*16 + lr)*128 + cx1);
    if(stg){
      GLL(Bsw + (size_t)128*K + koff, nbc + 32768 + 16384 + sdst);
      GLL(Bsw + (size_t)192*K + koff, nbc + 32768 + 24576 + sdst);
    }
    SCHEDB; __builtin_amdgcn_s_barrier();
    LGKM0; SCHEDB;
    __builtin_amdgcn_s_setprio(1);
#pragma unroll
    for(int i = 0; i < 4; i++)
#pragma unroll
      for(int j = 0; j < 4; j++)
        acc[i][j] = __builtin_amdgcn_mfma_f32_16x16x32_bf16(afr[i], bf1[j], acc[i][j], 0, 0, 0);
    __builtin_amdgcn_s_setprio(0);
    if(stg){ VMCNT4; } else { VMCNT0; }
    SCHEDB; __builtin_amdgcn_s_barrier();

    // ---------- phase 2: Mhi k0 reads; stage A0,A2(t+1)
#pragma unroll
    for(int i = 0; i < 4; i++)
      afr[i] = *(const bf16x8*)(Ab + (wm*128 + 64 + i*16 + lr)*128 + cx0);
    if(stg){
      GLL(Asw + koff,                 nbc + sdst);
      GLL(Asw + (size_t)128*K + koff, nbc + 16384 + sdst);
    }
    SCHEDB; __builtin_amdgcn_s_barrier();
    LGKM0; SCHEDB;
    __builtin_amdgcn_s_setprio(1);
#pragma unroll
    for(int i = 0; i < 4; i++)
#pragma unroll
      for(int j = 0; j < 4; j++)
        acc[4+i][j] = __builtin_amdgcn_mfma_f32_16x16x32_bf16(afr[i], bf0[j], acc[4+i][j], 0, 0, 0);
    __builtin_amdgcn_s_setprio(0);
    SCHEDB; __builtin_amdgcn_s_barrier();

    // ---------- phase 3: Mhi k1 reads; stage A1,A3(t+1); vmcnt(2)
#pragma unroll
    for(int i = 0; i < 4; i++)
      afr[i] = *(const bf16x8*)(Ab + (wm*128 + 64 + i*16 + lr)*128 + cx1);
    if(stg){
      GLL(Asw + (size_t)64*K + koff,  nbc + 8192 + sdst);
      GLL(Asw + (size_t)192*K + koff, nbc + 24576 + sdst);
    }
    SCHEDB; __builtin_amdgcn_s_barrier();
    LGKM0; SCHEDB;
    __builtin_amdgcn_s_setprio(1);
#pragma unroll
    for(int i = 0; i < 4; i++)
#pragma unroll
      for(int j = 0; j < 4; j++)
        acc[4+i][j] = __builtin_amdgcn_mfma_f32_16x16x32_bf16(afr[i], bf1[j], acc[4+i][j], 0, 0, 0);
    __builtin_amdgcn_s_setprio(0);
    if(stg){ VMCNT2; }
    SCHEDB; __builtin_amdgcn_s_barrier();
  }

  // epilogue: split bf16 store (u | z)
#pragma unroll
  for(int fm = 0; fm < 8; fm++){
#pragma unroll
    for(int fn = 0; fn < 4; fn++){
      int cc = n0 + wn * 64 + fn * 16 + lr;
      int r0 = m0 + wm * 128 + fm * 16 + lg * 4;
#pragma unroll
      for(int j = 0; j < 4; j++){
        float v = acc[fm][fn][j];
        size_t rr = r0 + j;
        if(cc < 2048) Cu[rr * 2048 + cc] = f2bf(v);
        else          Cz[rr * 2048 + (cc - 2048)] = f2bf(v);
      }
    }
  }
}

// ---------- bf16 MFMA GEMM:  C[M][N] = A[M][K] * W[N][K]^T  (NT) ----------
// 128 x BN tile, BK=32, 4 waves as 2x2. Swizzle: (row>>1)&3 both-sides.
// EPI: 1 = bf16 store of softplus(acc + ep[n])   (dt_proj -> delta)
//      2 = f32 store of acc + ep[m*ldc+n]        (out_proj + residual)
template<int BN, int FN, int EPI>
__global__ __launch_bounds__(256) void gemm_nt(
    const u16* __restrict__ A, const u16* __restrict__ W,
    void* __restrict__ Cv, void* __restrict__ C2v,
    const float* __restrict__ ep, int K, int ldc)
{
  constexpr int WN   = BN / 2;
  constexpr int NCHB = (BN * 64) / 1024;
  __shared__ alignas(16) u16 As[128 * 32];
  __shared__ alignas(16) u16 Bs[BN * 32];

  const int tid  = threadIdx.x;
  const int wave = tid >> 6, lane = tid & 63;
  const int wm = wave >> 1, wn = wave & 1;
  const int lr = lane & 15, lg = lane >> 4;
  const int m0 = blockIdx.x * 128, n0 = blockIdx.y * BN;
  const int rsw = (lr >> 1) & 3;

  f32x4 acc[4][FN];
  const f32x4 z4 = {0.f, 0.f, 0.f, 0.f};
#pragma unroll
  for(int i = 0; i < 4; i++)
#pragma unroll
    for(int j = 0; j < FN; j++) acc[i][j] = z4;

  for(int k0 = 0; k0 < K; k0 += 32){
#pragma unroll
    for(int i = 0; i < 2; i++){
      int off = (wave + 4 * i) * 1024 + lane * 16;
      int row = off >> 6;
      int scl = 8 * (((off >> 4) & 3) ^ ((row >> 1) & 3));
      GLL(A + (size_t)(m0 + row) * K + k0 + scl, (char*)As + off);
    }
    for(int ch = wave; ch < NCHB; ch += 4){
      int off = ch * 1024 + lane * 16;
      int row = off >> 6;
      int scl = 8 * (((off >> 4) & 3) ^ ((row >> 1) & 3));
      GLL(W + (size_t)(n0 + row) * K + k0 + scl, (char*)Bs + off);
    }
    __syncthreads();

    bf16x8 af[4], bfr[FN];
#pragma unroll
    for(int fm = 0; fm < 4; fm++)
      af[fm] = *(const bf16x8*)(As + (wm * 64 + fm * 16 + lr) * 32 + (lg ^ rsw) * 8);
#pragma unroll
    for(int fn = 0; fn < FN; fn++)
      bfr[fn] = *(const bf16x8*)(Bs + (wn * WN + fn * 16 + lr) * 32 + (lg ^ rsw) * 8);
#pragma unroll
    for(int fm = 0; fm < 4; fm++)
#pragma unroll
      for(int fn = 0; fn < FN; fn++)
        acc[fm][fn] = __builtin_amdgcn_mfma_f32_16x16x32_bf16(af[fm], bfr[fn], acc[fm][fn], 0, 0, 0);
    __syncthreads();
  }

#pragma unroll
  for(int fm = 0; fm < 4; fm++){
#pragma unroll
    for(int fn = 0; fn < FN; fn++){
      int cc = n0 + wn * WN + fn * 16 + lr;
      int r0 = m0 + wm * 64 + fm * 16 + lg * 4;
      f32x4 a = acc[fm][fn];
#pragma unroll
      for(int j = 0; j < 4; j++){
        float v = a[j];
        int r = r0 + j;
        size_t idx = (size_t)r * ldc + cc;
        if constexpr(EPI == 1){
          ((u16*)Cv)[idx] = f2bf(softplusf(v + ep[cc]));
        } else {
          ((float*)Cv)[idx] = v + ep[idx];
        }
      }
    }
  }
}

// ---------- x_proj GEMM: 32x96 tile, 256 blocks; fused dt->bf16 + bc f32 ----
__global__ __launch_bounds__(256) void gemm_xp(
    const u16* __restrict__ A, const u16* __restrict__ W,
    u16* __restrict__ dtb, float* __restrict__ bc, int K)
{
  __shared__ alignas(16) u16 ABs[4096];   // 32 A-rows + 96 B-rows, 32 cols
  const int tid  = threadIdx.x;
  const int wave = tid >> 6, lane = tid & 63;
  const int wm = wave >> 1, wn = wave & 1;
  const int lr = lane & 15, lg = lane >> 4;
  const int m0 = blockIdx.x * 32;
  const int rsw = (lr >> 1) & 3;

  f32x4 acc[3];
  const f32x4 z4 = {0.f, 0.f, 0.f, 0.f};
#pragma unroll
  for(int j = 0; j < 3; j++) acc[j] = z4;

  for(int k0 = 0; k0 < K; k0 += 32){
#pragma unroll
    for(int i = 0; i < 2; i++){
      int off = tid * 16 + i * 4096;
      int row = off >> 6;
      int scl = 8 * (((off >> 4) & 3) ^ ((row >> 1) & 3));
      const u16* src = (row < 32)
        ? A + (size_t)(m0 + row) * K + k0 + scl
        : W + (size_t)(row - 32) * K + k0 + scl;
      GLL(src, (char*)ABs + off);
    }
    __syncthreads();
    bf16x8 af = *(const bf16x8*)(ABs + (wm * 16 + lr) * 32 + (lg ^ rsw) * 8);
    bf16x8 bfr[3];
#pragma unroll
    for(int fn = 0; fn < 3; fn++)
      bfr[fn] = *(const bf16x8*)(ABs + (32 + wn * 48 + fn * 16 + lr) * 32 + (lg ^ rsw) * 8);
#pragma unroll
    for(int fn = 0; fn < 3; fn++)
      acc[fn] = __builtin_amdgcn_mfma_f32_16x16x32_bf16(af, bfr[fn], acc[fn], 0, 0, 0);
    __syncthreads();
  }

#pragma unroll
  for(int fn = 0; fn < 3; fn++){
    int cc = wn * 48 + fn * 16 + lr;
    int r0 = m0 + wm * 16 + lg * 4;
#pragma unroll
    for(int j = 0; j < 4; j++){
      float v = acc[fn][j];
      size_t rr = r0 + j;
      if(cc < 64) dtb[rr * 64 + cc] = f2bf(v);
      else        bc[rr * 32 + (cc - 64)] = v;
    }
  }
}

// ---------- depthwise causal conv (k=4) + bias + SiLU, bf16 in/out ----------
__global__ __launch_bounds__(256) void conv_kernel(
    const u16* __restrict__ ub, const float* __restrict__ cw,
    const float* __restrict__ cb, u16* __restrict__ uc)
{
  const int m = blockIdx.x;
  const int l = m & 2047;
  const int d0 = threadIdx.x * 8;
  float4 w4[8];
#pragma unroll
  for(int i = 0; i < 8; i++) w4[i] = *(const float4*)(cw + (size_t)(d0 + i) * 4);
  float r[4][8];
#pragma unroll
  for(int j = 0; j < 4; j++)
#pragma unroll
    for(int i = 0; i < 8; i++) r[j][i] = 0.f;
  for(int j = 0; j < 4; j++){
    if(l - 3 + j < 0) continue;
    uint4 a = *(const uint4*)(ub + (size_t)(m - 3 + j) * 2048 + d0);
    u32 w0 = a.x, w1 = a.y, w2 = a.z, w3 = a.w;
    r[j][0] = bf2f((u16)(w0 & 0xffff)); r[j][1] = bf2f((u16)(w0 >> 16));
    r[j][2] = bf2f((u16)(w1 & 0xffff)); r[j][3] = bf2f((u16)(w1 >> 16));
    r[j][4] = bf2f((u16)(w2 & 0xffff)); r[j][5] = bf2f((u16)(w2 >> 16));
    r[j][6] = bf2f((u16)(w3 & 0xffff)); r[j][7] = bf2f((u16)(w3 >> 16));
  }
  float4 b0 = *(const float4*)(cb + d0), b1 = *(const float4*)(cb + d0 + 4);
  float bb[8] = {b0.x, b0.y, b0.z, b0.w, b1.x, b1.y, b1.z, b1.w};
  u32 outw[4];
#pragma unroll
  for(int i = 0; i < 4; i++){
    int e0 = 2 * i, e1 = 2 * i + 1;
    float v0 = bb[e0] + r[0][e0]*w4[e0].x + r[1][e0]*w4[e0].y + r[2][e0]*w4[e0].z + r[3][e0]*w4[e0].w;
    float v1 = bb[e1] + r[0][e1]*w4[e1].x + r[1][e1]*w4[e1].y + r[2][e1]*w4[e1].z + r[3][e1]*w4[e1].w;
    outw[i] = (u32)f2bf(siluf(v0)) | ((u32)f2bf(siluf(v1)) << 16);
  }
  uint4 o = {outw[0], outw[1], outw[2], outw[3]};
  *(uint4*)(uc + (size_t)m * 2048 + d0) = o;
}

// ================= selective scan: chunk-parallel, 1 lane = 1 channel ======
__global__ __launch_bounds__(256) void scanA_kernel(
    const u16* __restrict__ deltab, const u16* __restrict__ uc,
    const float* __restrict__ bc, const float* __restrict__ A_log,
    float* __restrict__ Hc, float* __restrict__ Pc)
{
  __shared__ u16   sd[16][256];
  __shared__ u16   su[16][256];
  __shared__ float sB[16][16];
  const int tid = threadIdx.x;
  const int dg = blockIdx.x, chunk = blockIdx.y, b = blockIdx.z;
  const int d  = dg * 256 + tid;

  float a2[16], h[16], P[16];
#pragma unroll
  for(int q = 0; q < 4; q++){
    float4 al = *(const float4*)(A_log + (size_t)d * 16 + q * 4);
    a2[q*4+0] = -expf(al.x) * 1.44269504f;
    a2[q*4+1] = -expf(al.y) * 1.44269504f;
    a2[q*4+2] = -expf(al.z) * 1.44269504f;
    a2[q*4+3] = -expf(al.w) * 1.44269504f;
  }
#pragma unroll
  for(int s = 0; s < 16; s++){ h[s] = 0.f; P[s] = 1.f; }

  for(int w = 0; w < 8; w++){
    const size_t m0 = (size_t)b * 2048 + chunk * 128 + w * 16;
#pragma unroll
    for(int i = 0; i < 2; i++){
      int fo = tid + i * 256;
      int row = fo >> 5, col = (fo & 31) * 8;
      *(uint4*)&sd[row][col] = *(const uint4*)(deltab + (m0 + row) * 2048 + dg * 256 + col);
      *(uint4*)&su[row][col] = *(const uint4*)(uc     + (m0 + row) * 2048 + dg * 256 + col);
    }
    if(tid < 64){
      int row = tid >> 2, col = (tid & 3) * 4;
      *(float4*)&sB[row][col] = *(const float4*)(bc + (m0 + row) * 32 + col);
    }
    __syncthreads();
#pragma unroll 2
    for(int l = 0; l < 16; l++){
      float dt = bf2f(sd[l][tid]);
      float u  = bf2f(su[l][tid]);
      float du = dt * u;
      float4 B0 = *(const float4*)&sB[l][0];
      float4 B1 = *(const float4*)&sB[l][4];
      float4 B2 = *(const float4*)&sB[l][8];
      float4 B3 = *(const float4*)&sB[l][12];
      float Bv[16] = {B0.x,B0.y,B0.z,B0.w,B1.x,B1.y,B1.z,B1.w,
                      B2.x,B2.y,B2.z,B2.w,B3.x,B3.y,B3.z,B3.w};
#pragma unroll
      for(int s = 0; s < 16; s++){
        float e = exp2fast(dt * a2[s]);
        P[s] *= e;
        h[s] = __builtin_fmaf(e, h[s], du * Bv[s]);
      }
    }
    __syncthreads();
  }
  const size_t base = (((size_t)b * 16 + chunk) * 2048 + d) * 16;
#pragma unroll
  for(int q = 0; q < 4; q++){
    float4 hv = {h[q*4], h[q*4+1], h[q*4+2], h[q*4+3]};
    float4 pv = {P[q*4], P[q*4+1], P[q*4+2], P[q*4+3]};
    *(float4*)(Hc + base + q * 4) = hv;
    *(float4*)(Pc + base + q * 4) = pv;
  }
}

__global__ __launch_bounds__(256) void scanB_kernel(
    const float* __restrict__ Hc, const float* __restrict__ Pc,
    float* __restrict__ Hin)
{
  const int e = blockIdx.x * 256 + threadIdx.x;
  const int b = e >> 15, rem = e & 32767;
  float hin = 0.f;
  for(int c = 0; c < 16; c++){
    size_t idx = (((size_t)b * 16 + c) << 15) + rem;
    Hin[idx] = hin;
    hin = __builtin_fmaf(Pc[idx], hin, Hc[idx]);
  }
}

__global__ __launch_bounds__(256) void scanC_kernel(
    const u16* __restrict__ deltab, const u16* __restrict__ uc,
    const float* __restrict__ bc, const u16* __restrict__ zb,
    const float* __restrict__ A_log, const float* __restrict__ Dv,
    const float* __restrict__ Hin, u16* __restrict__ ybf)
{
  __shared__ u16   sd[16][256];
  __shared__ u16   su[16][256];
  __shared__ u16   sz[16][256];
  __shared__ float sBC[16][32];
  __shared__ u16   sy[16][256];
  const int tid = threadIdx.x;
  const int dg = blockIdx.x, chunk = blockIdx.y, b = blockIdx.z;
  const int d  = dg * 256 + tid;

  float a2[16], h[16];
#pragma unroll
  for(int q = 0; q < 4; q++){
    float4 al = *(const float4*)(A_log + (size_t)d * 16 + q * 4);
    a2[q*4+0] = -expf(al.x) * 1.44269504f;
    a2[q*4+1] = -expf(al.y) * 1.44269504f;
    a2[q*4+2] = -expf(al.z) * 1.44269504f;
    a2[q*4+3] = -expf(al.w) * 1.44269504f;
  }
  const size_t hbase = (((size_t)b * 16 + chunk) * 2048 + d) * 16;
#pragma unroll
  for(int q = 0; q < 4; q++){
    float4 hv = *(const float4*)(Hin + hbase + q * 4);
    h[q*4] = hv.x; h[q*4+1] = hv.y; h[q*4+2] = hv.z; h[q*4+3] = hv.w;
  }
  const float Dd = Dv[d];

  for(int w = 0; w < 8; w++){
    const size_t m0 = (size_t)b * 2048 + chunk * 128 + w * 16;
#pragma unroll
    for(int i = 0; i < 2; i++){
      int fo = tid + i * 256;
      int row = fo >> 5, col = (fo & 31) * 8;
      *(uint4*)&sd[row][col] = *(const uint4*)(deltab + (m0 + row) * 2048 + dg * 256 + col);
      *(uint4*)&su[row][col] = *(const uint4*)(uc     + (m0 + row) * 2048 + dg * 256 + col);
      *(uint4*)&sz[row][col] = *(const uint4*)(zb     + (m0 + row) * 2048 + dg * 256 + col);
    }
    if(tid < 128){
      int row = tid >> 3, col = (tid & 7) * 4;
      *(float4*)&sBC[row][col] = *(const float4*)(bc + (m0 + row) * 32 + col);
    }
    __syncthreads();
#pragma unroll 2
    for(int l = 0; l < 16; l++){
      float dt = bf2f(sd[l][tid]);
      float u  = bf2f(su[l][tid]);
      float du = dt * u;
      float4 B0 = *(const float4*)&sBC[l][0];
      float4 B1 = *(const float4*)&sBC[l][4];
      float4 B2 = *(const float4*)&sBC[l][8];
      float4 B3 = *(const float4*)&sBC[l][12];
      float4 C0 = *(const float4*)&sBC[l][16];
      float4 C1 = *(const float4*)&sBC[l][20];
      float4 C2 = *(const float4*)&sBC[l][24];
      float4 C3 = *(const float4*)&sBC[l][28];
      float Bv[16] = {B0.x,B0.y,B0.z,B0.w,B1.x,B1.y,B1.z,B1.w,
                      B2.x,B2.y,B2.z,B2.w,B3.x,B3.y,B3.z,B3.w};
      float Cv[16] = {C0.x,C0.y,C0.z,C0.w,C1.x,C1.y,C1.z,C1.w,
                      C2.x,C2.y,C2.z,C2.w,C3.x,C3.y,C3.z,C3.w};
      float y = 0.f;
#pragma unroll
      for(int s = 0; s < 16; s++){
        float e = exp2fast(dt * a2[s]);
        h[s] = __builtin_fmaf(e, h[s], du * Bv[s]);
        y = __builtin_fmaf(h[s], Cv[s], y);
      }
      float z = bf2f(sz[l][tid]);
      y = (y + Dd * u) * siluf(z);
      sy[l][tid] = f2bf(y);
    }
    __syncthreads();
#pragma unroll
    for(int i = 0; i < 2; i++){
      int fo = tid + i * 256;
      int row = fo >> 5, col = (fo & 31) * 8;
      *(uint4*)(ybf + (m0 + row) * 2048 + dg * 256 + col) = *(const uint4*)&sy[row][col];
    }
  }
}

// ---------- launch ----------
extern "C" void kernel_launch(void* const* d_in, const int* in_sizes, int n_in,
                              void* d_out, int out_size, void* d_ws, size_t ws_size,
                              hipStream_t stream) {
  (void)in_sizes; (void)n_in; (void)out_size; (void)ws_size;
  const float* x         = (const float*)d_in[0];
  const float* norm_w    = (const float*)d_in[1];
  const float* norm_b    = (const float*)d_in[2];
  const float* in_proj_w = (const float*)d_in[3];
  const float* conv_w    = (const float*)d_in[4];
  const float* conv_b    = (const float*)d_in[5];
  const float* x_proj_w  = (const float*)d_in[6];
  const float* dt_proj_w = (const float*)d_in[7];
  const float* dt_proj_b = (const float*)d_in[8];
  const float* A_log     = (const float*)d_in[9];
  const float* Dv        = (const float*)d_in[10];
  const float* out_proj_w= (const float*)d_in[11];
  float* out = (float*)d_out;

  // workspace layout (~183 MB total)
  char* ws = (char*)d_ws;
  u16*   w_in  = (u16*)ws;  ws += (size_t)4096 * 1024 * 2;
  u16*   w_xp  = (u16*)ws;  ws += (size_t)96 * 2048 * 2;
  u16*   w_dt  = (u16*)ws;  ws += (size_t)2048 * 64 * 2;
  u16*   w_op  = (u16*)ws;  ws += (size_t)1024 * 2048 * 2;
  u16*   xn    = (u16*)ws;  ws += (size_t)8192 * 1024 * 2;
  u16*   u_bf  = (u16*)ws;  ws += (size_t)8192 * 2048 * 2;
  u16*   z_bf  = (u16*)ws;  ws += (size_t)8192 * 2048 * 2;
  u16*   ucbf  = (u16*)ws;  ws += (size_t)8192 * 2048 * 2;
  float* bc    = (float*)ws; ws += (size_t)8192 * 32 * 4;
  u16*   dtbf  = (u16*)ws;  ws += (size_t)8192 * 64 * 2;
  u16*   deltab= (u16*)ws;  ws += (size_t)8192 * 2048 * 2;
  float* Hc    = (float*)ws; ws += (size_t)4 * 16 * 2048 * 16 * 4;
  float* Pc    = (float*)ws; ws += (size_t)4 * 16 * 2048 * 16 * 4;
  float* Hin   = (float*)xn;   // dead after in_proj
  u16*   ybf   = u_bf;         // u dead after conv

  // weight conversions
  f2bf_kernel<<<16384, 256, 0, stream>>>(in_proj_w,  w_in, 4096 * 1024);
  f2bf_kernel<<<768,   256, 0, stream>>>(x_proj_w,   w_xp, 96 * 2048);
  f2bf_kernel<<<512,   256, 0, stream>>>(dt_proj_w,  w_dt, 2048 * 64);
  f2bf_kernel<<<8192,  256, 0, stream>>>(out_proj_w, w_op, 1024 * 2048);

  // 1. layernorm -> bf16
  ln_kernel<<<8192, 256, 0, stream>>>(x, norm_w, norm_b, xn);
  // 2. in_proj (256x256 BK=64 4-phase): u/z bf16 halves
  gemm256<<<512, 512, 0, stream>>>(xn, w_in, u_bf, z_bf, 1024, 16);
  // 3. depthwise conv + SiLU -> bf16
  conv_kernel<<<8192, 256, 0, stream>>>(u_bf, conv_w, conv_b, ucbf);
  // 4. x_proj fused: dt->bf16, B/C -> bc f32
  gemm_xp<<<256, 256, 0, stream>>>(ucbf, w_xp, dtbf, bc, 2048);
  // 5. dt_proj + bias + softplus -> bf16 delta
  gemm_nt<128, 4, 1><<<dim3(64, 16), 256, 0, stream>>>(dtbf, w_dt, deltab, nullptr, dt_proj_b, 64, 2048);
  // 6. selective scan: chunk-parallel 3-pass
  scanA_kernel<<<dim3(8, 16, 4), 256, 0, stream>>>(deltab, ucbf, bc, A_log, Hc, Pc);
  scanB_kernel<<<512, 256, 0, stream>>>(Hc, Pc, Hin);
  scanC_kernel<<<dim3(8, 16, 4), 256, 0, stream>>>(deltab, ucbf, bc, z_bf, A_log, Dv, Hin, ybf);
  // 7. out_proj + residual
  gemm_nt<128, 4, 2><<<dim3(64, 8), 256, 0, stream>>>(ybf, w_op, out, nullptr, x, 2048, 1024);
}